// Round 17
// baseline (533.655 us; speedup 1.0000x reference)
//
#include <hip/hip_runtime.h>
#include <math.h>

#define N_NODES 100000
#define N_EDGES 1600000
#define NB 64
#define F_IN 128
#define HDIM 64
#define NC 10

#define BSHIFT 9
#define BUCKET_NODES (1 << BSHIFT)                          // 512
#define NBUCK ((N_NODES + BUCKET_NODES - 1) >> BSHIFT)      // 196
#define EW_CHUNK 4096
#define EW_GRID ((N_EDGES + EW_CHUNK - 1) / EW_CHUNK)       // 391
#define POOL_NPW 16

typedef __attribute__((ext_vector_type(8))) short bf16x8;
typedef __attribute__((ext_vector_type(4))) float f32x4;

// ---------- bf16 helpers ----------
__device__ __forceinline__ unsigned short f2bf(float f) {
    unsigned u = __float_as_uint(f);
    u += 0x7FFFu + ((u >> 16) & 1u);    // round to nearest even
    return (unsigned short)(u >> 16);
}
__device__ __forceinline__ float bf2f(unsigned short b) {
    return __uint_as_float((unsigned)b << 16);
}

// ---------- W split: W -> bf16 hi + bf16 lo (residual) ----------
__global__ __launch_bounds__(256) void wsplit(
    const float* __restrict__ W0, const float* __restrict__ W1,
    const float* __restrict__ W2, const float* __restrict__ W3,
    unsigned short* __restrict__ hi, unsigned short* __restrict__ lo, int n)
{
    int i = blockIdx.x * 256 + threadIdx.x;
    if (i >= 4 * n) return;
    const float* Ws[4] = {W0, W1, W2, W3};
    float w = Ws[i / n][i % n];
    unsigned short h = f2bf(w);
    hi[i] = h;
    lo[i] = f2bf(w - bf2f(h));
}

// ---------- fused q/k/v/skip GEMM via MFMA (bf16 3-term residual) ----------
// Wave = 32 rows (2 row-tiles); block = 128 rows, ALL 4 mats (X read+split once).
// B staged per-mat into LDS (8*NCH KB: 32KB l0 / 16KB l1,l2) -> 4-5 blocks/CU
// (r16's 64KB whole-B staging capped at 2 blocks/CU -> latency-bound at 17.6%).
// Fragment-permuted layout: lds[fb*1024B + lane*16B], conflict-free ds_read_b128.
// out = Xhi*Whi + Xlo*Whi + Xhi*Wlo  (fp32 MFMA accumulate).
template<int K>
__global__ __launch_bounds__(256) void qkvs_gemm_mfma(
    const float* __restrict__ xin,
    const unsigned short* __restrict__ whi,
    const unsigned short* __restrict__ wlo,
    const float* __restrict__ bq, const float* __restrict__ bk,
    const float* __restrict__ bv, const float* __restrict__ bs,
    float* __restrict__ q, unsigned short* __restrict__ k16,
    unsigned short* __restrict__ v16, float* __restrict__ sk)
{
    constexpr int NCH = K / 32;
    constexpr int NFB = 4 * NCH * 2;        // per-mat: col-tiles * chunks * (hi,lo)
    __shared__ short Blds[NFB * 512];       // 1 KB per fragment-block

    const int tid = threadIdx.x;
    const int wv  = tid >> 6;
    const int l   = tid & 63;
    const int lr  = l & 15;      // A-row / B-col / D-col within tile
    const int lg  = l >> 4;      // k-group (8 consecutive k) ; D-row group
    const int row0 = blockIdx.x * 128 + wv * 32;

    // ---- load X rows, split into bf16 hi/lo fragments (once per block) ----
    bf16x8 Ahi[2][NCH], Alo[2][NCH];
    #pragma unroll
    for (int rt = 0; rt < 2; rt++) {
        int row = row0 + rt * 16 + lr;
        bool ok = row < N_NODES;
        const float* xr = xin + (size_t)(ok ? row : 0) * K + lg * 8;
        #pragma unroll
        for (int c = 0; c < NCH; c++) {
            float4 f0, f1;
            if (ok) {
                f0 = *(const float4*)(xr + c * 32);
                f1 = *(const float4*)(xr + c * 32 + 4);
            } else {
                f0 = make_float4(0.f, 0.f, 0.f, 0.f);
                f1 = f0;
            }
            float xv[8] = {f0.x, f0.y, f0.z, f0.w, f1.x, f1.y, f1.z, f1.w};
            #pragma unroll
            for (int j = 0; j < 8; j++) {
                unsigned short hb = f2bf(xv[j]);
                Ahi[rt][c][j] = (short)hb;
                Alo[rt][c][j] = (short)f2bf(xv[j] - bf2f(hb));
            }
        }
    }

    const float* Bm[4] = {bq, bk, bv, bs};

    for (int mat = 0; mat < 4; mat++) {
        if (mat) __syncthreads();           // protect Blds from previous reads
        // ---- stage this mat's B fragment-blocks (each wave stages NFB/4) ----
        #pragma unroll
        for (int it = 0; it < NFB / 4; it++) {
            int fb   = it * 4 + wv;
            int hsel = fb & 1;
            int rest = fb >> 1;             // ct*NCH + c
            int c    = rest & (NCH - 1);
            int ct   = rest / NCH;
            const unsigned short* src = hsel ? wlo : whi;
            size_t goff = (size_t)(mat * 64 + ct * 16 + lr) * K + c * 32 + lg * 8;
            uint4 d = *(const uint4*)&src[goff];
            *(uint4*)&Blds[fb * 512 + l * 8] = d;
        }
        __syncthreads();

        #pragma unroll
        for (int ct = 0; ct < 4; ct++) {
            f32x4 acc0 = {0.f, 0.f, 0.f, 0.f};
            f32x4 acc1 = {0.f, 0.f, 0.f, 0.f};
            #pragma unroll
            for (int c = 0; c < NCH; c++) {
                const int fb = (ct * NCH + c) << 1;
                bf16x8 Bhi = *(const bf16x8*)&Blds[fb * 512 + l * 8];
                bf16x8 Blo = *(const bf16x8*)&Blds[(fb + 1) * 512 + l * 8];
                acc0 = __builtin_amdgcn_mfma_f32_16x16x32_bf16(Ahi[0][c], Bhi, acc0, 0, 0, 0);
                acc1 = __builtin_amdgcn_mfma_f32_16x16x32_bf16(Ahi[1][c], Bhi, acc1, 0, 0, 0);
                acc0 = __builtin_amdgcn_mfma_f32_16x16x32_bf16(Alo[0][c], Bhi, acc0, 0, 0, 0);
                acc1 = __builtin_amdgcn_mfma_f32_16x16x32_bf16(Alo[1][c], Bhi, acc1, 0, 0, 0);
                acc0 = __builtin_amdgcn_mfma_f32_16x16x32_bf16(Ahi[0][c], Blo, acc0, 0, 0, 0);
                acc1 = __builtin_amdgcn_mfma_f32_16x16x32_bf16(Ahi[1][c], Blo, acc1, 0, 0, 0);
            }
            float bias = Bm[mat][ct * 16 + lr];
            int colo = ct * 16 + lr;
            // D layout: row = rt*16 + lg*4 + i, col = lr (within tile)
            #pragma unroll
            for (int i = 0; i < 4; i++) {
                int row = row0 + lg * 4 + i;
                if (row < N_NODES) {
                    float val = acc0[i] + bias;
                    size_t off = (size_t)row * HDIM + colo;
                    if (mat == 0)      q[off]   = val;
                    else if (mat == 1) k16[off] = f2bf(val);
                    else if (mat == 2) v16[off] = f2bf(val);
                    else               sk[off]  = val;
                }
            }
            #pragma unroll
            for (int i = 0; i < 4; i++) {
                int row = row0 + 16 + lg * 4 + i;
                if (row < N_NODES) {
                    float val = acc1[i] + bias;
                    size_t off = (size_t)row * HDIM + colo;
                    if (mat == 0)      q[off]   = val;
                    else if (mat == 1) k16[off] = f2bf(val);
                    else if (mat == 2) v16[off] = f2bf(val);
                    else               sk[off]  = val;
                }
            }
        }
    }
}

// ---------- CSR build, stage 1: per-bucket edge counts (LDS hist only) ----------
__global__ __launch_bounds__(256) void count_bucket(
    const int* __restrict__ ei, int* __restrict__ bcnt)
{
    __shared__ int hist[NBUCK];
    for (int i = threadIdx.x; i < NBUCK; i += 256) hist[i] = 0;
    __syncthreads();
    int e0 = blockIdx.x * EW_CHUNK;
    #pragma unroll
    for (int i = 0; i < EW_CHUNK / 256; i++) {
        int e = e0 + i * 256 + threadIdx.x;
        if (e < N_EDGES) atomicAdd(&hist[ei[N_EDGES + e] >> BSHIFT], 1);
    }
    __syncthreads();
    for (int i = threadIdx.x; i < NBUCK; i += 256)
        if (hist[i]) atomicAdd(&bcnt[i], hist[i]);
}

// ---------- CSR build, stage 2: bucket base scan (196 values, one block) ----------
__global__ __launch_bounds__(256) void scan_bucket(
    const int* __restrict__ bcnt, int* __restrict__ bbase, int* __restrict__ gcursor)
{
    __shared__ int sh[256];
    int t = threadIdx.x;
    int v = (t < NBUCK) ? bcnt[t] : 0;
    sh[t] = v;
    __syncthreads();
    for (int off = 1; off < 256; off <<= 1) {
        int u = (t >= off) ? sh[t - off] : 0;
        __syncthreads();
        sh[t] += u;
        __syncthreads();
    }
    if (t < NBUCK) { bbase[t] = sh[t] - v; gcursor[t] = sh[t] - v; }
}

// ---------- CSR build, stage 3: scatter packed edges into bucket order ----------
// packed entry: (dst_local << 17) | src
__global__ __launch_bounds__(256) void bucket_scatter(
    const int* __restrict__ ei, int* __restrict__ gcursor, int* __restrict__ bedge)
{
    __shared__ int hist[NBUCK];
    __shared__ int base[NBUCK];
    for (int i = threadIdx.x; i < NBUCK; i += 256) hist[i] = 0;
    __syncthreads();
    int e0 = blockIdx.x * EW_CHUNK;
    #pragma unroll
    for (int i = 0; i < EW_CHUNK / 256; i++) {
        int e = e0 + i * 256 + threadIdx.x;
        if (e < N_EDGES) atomicAdd(&hist[ei[N_EDGES + e] >> BSHIFT], 1);
    }
    __syncthreads();
    for (int i = threadIdx.x; i < NBUCK; i += 256)
        base[i] = hist[i] ? atomicAdd(&gcursor[i], hist[i]) : 0;
    __syncthreads();
    for (int i = threadIdx.x; i < NBUCK; i += 256) hist[i] = 0;
    __syncthreads();
    #pragma unroll
    for (int i = 0; i < EW_CHUNK / 256; i++) {
        int e = e0 + i * 256 + threadIdx.x;
        if (e < N_EDGES) {
            int src = ei[e];
            int dst = ei[N_EDGES + e];
            int b = dst >> BSHIFT;
            int pos = base[b] + atomicAdd(&hist[b], 1);
            bedge[pos] = ((dst & (BUCKET_NODES - 1)) << 17) | src;
        }
    }
}

// ---------- CSR build, stage 4: one WG per bucket ----------
__global__ __launch_bounds__(256) void csr_from_buckets(
    const int* __restrict__ bedge, const int* __restrict__ bbase,
    const int* __restrict__ bcnt, int* __restrict__ row_ptr,
    int* __restrict__ csr_src)
{
    __shared__ int cur[BUCKET_NODES];   // 512
    __shared__ int psum[256];
    const int b = blockIdx.x;
    const int dst0 = b << BSHIFT;
    const int t = threadIdx.x;

    for (int i = t; i < BUCKET_NODES; i += 256) cur[i] = 0;
    __syncthreads();

    const int beg = bbase[b], cnt = bcnt[b];
    for (int i = t; i < cnt; i += 256)
        atomicAdd(&cur[bedge[beg + i] >> 17], 1);
    __syncthreads();

    int a0 = cur[2 * t], a1 = cur[2 * t + 1];
    int pair = a0 + a1;
    psum[t] = pair;
    __syncthreads();
    for (int off = 1; off < 256; off <<= 1) {
        int u = (t >= off) ? psum[t - off] : 0;
        __syncthreads();
        psum[t] += u;
        __syncthreads();
    }
    int ex = psum[t] - pair;            // exclusive prefix of this pair

    int d0 = dst0 + 2 * t, d1 = d0 + 1;
    int g0 = beg + ex, g1 = beg + ex + a0;
    if (d0 < N_NODES) row_ptr[d0] = g0;
    if (d1 < N_NODES) row_ptr[d1] = g1;
    if (b == gridDim.x - 1 && t == 255) row_ptr[N_NODES] = beg + psum[255];
    cur[2 * t] = g0;
    cur[2 * t + 1] = g1;
    __syncthreads();

    for (int i = t; i < cnt; i += 256) {
        int ed = bedge[beg + i];
        int pos = atomicAdd(&cur[ed >> 17], 1);
        csr_src[pos] = ed & 0x1FFFF;
    }
}

// ---------- fused attention: wave per dst, 8 edges/iter, bf16 k/v gathers ----------
__global__ __launch_bounds__(256) void attn_fused(
    const int* __restrict__ row_ptr, const int* __restrict__ csr_src,
    const float* __restrict__ q, const unsigned short* __restrict__ k16,
    const unsigned short* __restrict__ v16, const float* __restrict__ skip,
    float* __restrict__ hout, int do_relu)
{
    int n = blockIdx.x * 4 + (threadIdx.x >> 6);
    if (n >= N_NODES) return;
    int lane = threadIdx.x & 63;
    int g = lane >> 3;
    int t = lane & 7;
    int beg = row_ptr[n], end = row_ptr[n + 1];

    const float* qrow = &q[(size_t)n * HDIM + t * 8];
    float4 qa = *(const float4*)qrow;
    float4 qb = *(const float4*)(qrow + 4);
    float m = -1e30f, s = 0.f;
    float4 aca = make_float4(0.f, 0.f, 0.f, 0.f);
    float4 acb = make_float4(0.f, 0.f, 0.f, 0.f);

    for (int i = beg; i < end; i += 8) {
        int e = i + g;
        bool valid = (e < end);
        int src = csr_src[valid ? e : beg];
        uint4 ku = *(const uint4*)&k16[(size_t)src * HDIM + t * 8];
        uint4 vu = *(const uint4*)&v16[(size_t)src * HDIM + t * 8];
        float p = qa.x * __uint_as_float(ku.x << 16)
                + qa.y * __uint_as_float(ku.x & 0xFFFF0000u)
                + qa.z * __uint_as_float(ku.y << 16)
                + qa.w * __uint_as_float(ku.y & 0xFFFF0000u)
                + qb.x * __uint_as_float(ku.z << 16)
                + qb.y * __uint_as_float(ku.z & 0xFFFF0000u)
                + qb.z * __uint_as_float(ku.w << 16)
                + qb.w * __uint_as_float(ku.w & 0xFFFF0000u);
        p += __shfl_xor(p, 1, 64);
        p += __shfl_xor(p, 2, 64);
        p += __shfl_xor(p, 4, 64);
        float a = valid ? p * 0.125f : -INFINITY;
        float mn = fmaxf(m, a);
        float sc = __expf(m - mn);
        float ew = __expf(a - mn);
        s = s * sc + ew;
        aca.x = aca.x * sc + ew * __uint_as_float(vu.x << 16);
        aca.y = aca.y * sc + ew * __uint_as_float(vu.x & 0xFFFF0000u);
        aca.z = aca.z * sc + ew * __uint_as_float(vu.y << 16);
        aca.w = aca.w * sc + ew * __uint_as_float(vu.y & 0xFFFF0000u);
        acb.x = acb.x * sc + ew * __uint_as_float(vu.z << 16);
        acb.y = acb.y * sc + ew * __uint_as_float(vu.z & 0xFFFF0000u);
        acb.z = acb.z * sc + ew * __uint_as_float(vu.w << 16);
        acb.w = acb.w * sc + ew * __uint_as_float(vu.w & 0xFFFF0000u);
        m = mn;
    }

    #pragma unroll
    for (int off = 8; off <= 32; off <<= 1) {
        float m2 = __shfl_xor(m, off, 64);
        float s2 = __shfl_xor(s, off, 64);
        float x0 = __shfl_xor(aca.x, off, 64);
        float x1 = __shfl_xor(aca.y, off, 64);
        float x2 = __shfl_xor(aca.z, off, 64);
        float x3 = __shfl_xor(aca.w, off, 64);
        float x4 = __shfl_xor(acb.x, off, 64);
        float x5 = __shfl_xor(acb.y, off, 64);
        float x6 = __shfl_xor(acb.z, off, 64);
        float x7 = __shfl_xor(acb.w, off, 64);
        float mn = fmaxf(m, m2);
        float c1 = __expf(m - mn);
        float c2 = __expf(m2 - mn);
        s = s * c1 + s2 * c2;
        aca.x = aca.x * c1 + x0 * c2;
        aca.y = aca.y * c1 + x1 * c2;
        aca.z = aca.z * c1 + x2 * c2;
        aca.w = aca.w * c1 + x3 * c2;
        acb.x = acb.x * c1 + x4 * c2;
        acb.y = acb.y * c1 + x5 * c2;
        acb.z = acb.z * c1 + x6 * c2;
        acb.w = acb.w * c1 + x7 * c2;
        m = mn;
    }

    if (g == 0) {
        float inv = (s > 0.f) ? (1.f / s) : 0.f;
        const float* skrow = &skip[(size_t)n * HDIM + t * 8];
        float4 s0 = *(const float4*)skrow;
        float4 s1 = *(const float4*)(skrow + 4);
        float4 o0, o1;
        o0.x = aca.x * inv + s0.x;
        o0.y = aca.y * inv + s0.y;
        o0.z = aca.z * inv + s0.z;
        o0.w = aca.w * inv + s0.w;
        o1.x = acb.x * inv + s1.x;
        o1.y = acb.y * inv + s1.y;
        o1.z = acb.z * inv + s1.z;
        o1.w = acb.w * inv + s1.w;
        if (do_relu) {
            o0.x = fmaxf(o0.x, 0.f); o0.y = fmaxf(o0.y, 0.f);
            o0.z = fmaxf(o0.z, 0.f); o0.w = fmaxf(o0.w, 0.f);
            o1.x = fmaxf(o1.x, 0.f); o1.y = fmaxf(o1.y, 0.f);
            o1.z = fmaxf(o1.z, 0.f); o1.w = fmaxf(o1.w, 0.f);
        }
        float* orow = &hout[(size_t)n * HDIM + t * 8];
        *(float4*)orow = o0;
        *(float4*)(orow + 4) = o1;
    }
}

// ---------- mean pool: run-length accumulate, 16 nodes/wave ----------
__global__ __launch_bounds__(256) void pool_kernel(
    const float* __restrict__ h, const int* __restrict__ batch,
    float* __restrict__ sums, float* __restrict__ cnt)
{
    int wid = blockIdx.x * 4 + (threadIdx.x >> 6);
    int n0 = wid * POOL_NPW;
    if (n0 >= N_NODES) return;
    int lane = threadIdx.x & 63;
    int nend = min(n0 + POOL_NPW, N_NODES);
    float acc = 0.f;
    int b_cur = batch[n0];
    int run = 0;
    for (int n = n0; n < nend; n++) {
        int b = batch[n];
        if (b != b_cur) {
            atomicAdd(&sums[b_cur * HDIM + lane], acc);
            if (lane == 0) atomicAdd(&cnt[b_cur], (float)run);
            acc = 0.f; run = 0; b_cur = b;
        }
        acc += h[(size_t)n * HDIM + lane];
        run++;
    }
    atomicAdd(&sums[b_cur * HDIM + lane], acc);
    if (lane == 0) atomicAdd(&cnt[b_cur], (float)run);
}

// ---------- head ----------
__global__ void head_kernel(
    const float* __restrict__ sums, const float* __restrict__ cnt,
    const float* __restrict__ Wl, const float* __restrict__ bl,
    float* __restrict__ out)
{
    int tid = threadIdx.x;
    if (tid >= NB * NC) return;
    int b = tid / NC, c = tid % NC;
    float cc = fmaxf(cnt[b], 1.0f);
    float acc = bl[c];
    #pragma unroll
    for (int f = 0; f < HDIM; f++)
        acc += (sums[b * HDIM + f] / cc) * Wl[c * HDIM + f];
    out[tid] = acc;
}

extern "C" void kernel_launch(void* const* d_in, const int* in_sizes, int n_in,
                              void* d_out, int out_size, void* d_ws, size_t ws_size,
                              hipStream_t stream)
{
    const float* x     = (const float*)d_in[0];
    const int*   ei    = (const int*)d_in[1];
    const int*   batch = (const int*)d_in[2];

    const float* W[3][4];
    const float* B[3][4];
    for (int l = 0; l < 3; l++)
        for (int j = 0; j < 4; j++) {
            W[l][j] = (const float*)d_in[3 + l * 8 + j * 2];
            B[l][j] = (const float*)d_in[3 + l * 8 + j * 2 + 1];
        }
    const float* Wl = (const float*)d_in[27];
    const float* bl = (const float*)d_in[28];
    float* out = (float*)d_out;

    const size_t NF = (size_t)N_NODES * HDIM;
    char* w = (char*)d_ws;
    float*          h       = (float*)w;          w += NF * 4;
    float*          q       = (float*)w;          w += NF * 4;
    unsigned short* k16     = (unsigned short*)w; w += NF * 2;
    unsigned short* v16     = (unsigned short*)w; w += NF * 2;
    float*          skip    = (float*)w;          w += NF * 4;
    int*            csr_src = (int*)w;            w += (size_t)N_EDGES * 4;
    int*            bedge   = (int*)w;            w += (size_t)N_EDGES * 4;
    int*            row_ptr = (int*)w;            w += (size_t)(N_NODES + 1) * 4;
    int*            bcnt    = (int*)w;            w += (size_t)NBUCK * 4;
    int*            bbase   = (int*)w;            w += (size_t)NBUCK * 4;
    int*            gcursor = (int*)w;            w += (size_t)NBUCK * 4;
    float*          sums    = (float*)w;          w += (size_t)NB * HDIM * 4;
    float*          cnt     = (float*)w;          w += (size_t)NB * 4;
    unsigned short* whi[3];
    unsigned short* wlo[3];
    const int wsz[3] = {64 * F_IN, 64 * HDIM, 64 * HDIM};   // per-mat elems
    for (int l = 0; l < 3; l++) {
        whi[l] = (unsigned short*)w; w += (size_t)4 * wsz[l] * 2;
        wlo[l] = (unsigned short*)w; w += (size_t)4 * wsz[l] * 2;
    }

    const int gemm_gx = (N_NODES + 127) / 128;
    const int node_gx = (N_NODES + 3) / 4;
    const int pool_gx = (N_NODES + POOL_NPW * 4 - 1) / (POOL_NPW * 4);

    // ----- W split to bf16 hi/lo (once) -----
    for (int l = 0; l < 3; l++) {
        int n = wsz[l];
        wsplit<<<(4 * n + 255) / 256, 256, 0, stream>>>(
            W[l][0], W[l][1], W[l][2], W[l][3], whi[l], wlo[l], n);
    }

    // ----- CSR build via LDS-staged counting sort (once; shared by all layers) -----
    hipMemsetAsync(bcnt, 0, (size_t)NBUCK * 4, stream);
    count_bucket<<<EW_GRID, 256, 0, stream>>>(ei, bcnt);
    scan_bucket<<<1, 256, 0, stream>>>(bcnt, bbase, gcursor);
    bucket_scatter<<<EW_GRID, 256, 0, stream>>>(ei, gcursor, bedge);
    csr_from_buckets<<<NBUCK, 256, 0, stream>>>(bedge, bbase, bcnt, row_ptr, csr_src);

    for (int l = 0; l < 3; l++) {
        if (l == 0) {
            qkvs_gemm_mfma<F_IN><<<gemm_gx, 256, 0, stream>>>(
                x, whi[0], wlo[0], B[0][0], B[0][1], B[0][2], B[0][3],
                q, k16, v16, skip);
        } else {
            qkvs_gemm_mfma<HDIM><<<gemm_gx, 256, 0, stream>>>(
                h, whi[l], wlo[l], B[l][0], B[l][1], B[l][2], B[l][3],
                q, k16, v16, skip);
        }
        attn_fused<<<node_gx, 256, 0, stream>>>(
            row_ptr, csr_src, q, k16, v16, skip, h, l < 2 ? 1 : 0);
    }

    hipMemsetAsync(sums, 0, (size_t)NB * HDIM * 4, stream);
    hipMemsetAsync(cnt,  0, (size_t)NB * 4, stream);
    pool_kernel<<<pool_gx, 256, 0, stream>>>(h, batch, sums, cnt);
    head_kernel<<<1, 640, 0, stream>>>(sums, cnt, Wl, bl, out);
}

// Round 18
// 444.885 us; speedup vs baseline: 1.1995x; 1.1995x over previous
//
#include <hip/hip_runtime.h>
#include <math.h>

#define N_NODES 100000
#define N_EDGES 1600000
#define NB 64
#define F_IN 128
#define HDIM 64
#define NC 10

#define BSHIFT 9
#define BUCKET_NODES (1 << BSHIFT)                          // 512
#define NBUCK ((N_NODES + BUCKET_NODES - 1) >> BSHIFT)      // 196
#define EW_CHUNK 4096
#define EW_GRID ((N_EDGES + EW_CHUNK - 1) / EW_CHUNK)       // 391

typedef __attribute__((ext_vector_type(8))) short bf16x8;
typedef __attribute__((ext_vector_type(4))) float f32x4;

// ---------- bf16 helpers ----------
__device__ __forceinline__ unsigned short f2bf(float f) {
    unsigned u = __float_as_uint(f);
    u += 0x7FFFu + ((u >> 16) & 1u);    // round to nearest even
    return (unsigned short)(u >> 16);
}
__device__ __forceinline__ float bf2f(unsigned short b) {
    return __uint_as_float((unsigned)b << 16);
}
__device__ __forceinline__ unsigned pack2bf(float a, float b) {
    return (unsigned)f2bf(a) | ((unsigned)f2bf(b) << 16);
}

// ---------- W split: W -> bf16 hi + bf16 lo (residual) ----------
__global__ __launch_bounds__(256) void wsplit(
    const float* __restrict__ W0, const float* __restrict__ W1,
    const float* __restrict__ W2, const float* __restrict__ W3,
    unsigned short* __restrict__ hi, unsigned short* __restrict__ lo, int n)
{
    int i = blockIdx.x * 256 + threadIdx.x;
    if (i >= 4 * n) return;
    const float* Ws[4] = {W0, W1, W2, W3};
    float w = Ws[i / n][i % n];
    unsigned short h = f2bf(w);
    hi[i] = h;
    lo[i] = f2bf(w - bf2f(h));
}

// ---------- fused q/k/v/skip GEMM via MFMA, OPERAND-SWAPPED ----------
// D = W·X^T: A = W fragment (from LDS, staged per mat), B = X fragment (regs).
// D layout: col = node (lane&15), row = feat (lg*4+i) -> each lane holds 4
// CONSECUTIVE output feats of one node => float4 / packed-bf16 vector stores
// (r13-r17 all pinned at ~84us independent of K; the K-invariant cost was the
// 128-scalar-store epilogue). Wave = 16 nodes; block = 64 nodes, all 4 mats.
// LDS = 8*NCH KB (32KB l0 / 16KB l1,l2). Grid 1563 -> ~6.1 waves/SIMD.
// out = Whi*Xhi + Wlo*Xhi + Whi*Xlo  (fp32 MFMA accumulate).
template<int K>
__global__ __launch_bounds__(256) void qkvs_gemm_mfma(
    const float* __restrict__ xin,
    const unsigned short* __restrict__ whi,
    const unsigned short* __restrict__ wlo,
    const float* __restrict__ bq, const float* __restrict__ bk,
    const float* __restrict__ bv, const float* __restrict__ bs,
    float* __restrict__ q, unsigned short* __restrict__ k16,
    unsigned short* __restrict__ v16, float* __restrict__ sk)
{
    constexpr int NCH = K / 32;
    constexpr int NFB = 4 * NCH * 2;        // per-mat: feat-tiles * chunks * (hi,lo)
    __shared__ short Wlds[NFB * 512];       // 1 KB per fragment-block

    const int tid = threadIdx.x;
    const int wv  = tid >> 6;
    const int l   = tid & 63;
    const int lr  = l & 15;      // B-col (node) / A-row (feat) / D-col (node)
    const int lg  = l >> 4;      // k-group (8 consecutive k); D-row group
    const int n0  = blockIdx.x * 64 + wv * 16;
    const int node = n0 + lr;
    const bool nok = node < N_NODES;

    // ---- load this wave's 16 X rows, split into bf16 hi/lo B-fragments ----
    bf16x8 Xhi[NCH], Xlo[NCH];
    {
        const float* xr = xin + (size_t)(nok ? node : 0) * K + lg * 8;
        #pragma unroll
        for (int c = 0; c < NCH; c++) {
            float4 f0, f1;
            if (nok) {
                f0 = *(const float4*)(xr + c * 32);
                f1 = *(const float4*)(xr + c * 32 + 4);
            } else {
                f0 = make_float4(0.f, 0.f, 0.f, 0.f);
                f1 = f0;
            }
            float xv[8] = {f0.x, f0.y, f0.z, f0.w, f1.x, f1.y, f1.z, f1.w};
            #pragma unroll
            for (int j = 0; j < 8; j++) {
                unsigned short hb = f2bf(xv[j]);
                Xhi[c][j] = (short)hb;
                Xlo[c][j] = (short)f2bf(xv[j] - bf2f(hb));
            }
        }
    }

    const float* Bm[4] = {bq, bk, bv, bs};

    for (int mat = 0; mat < 4; mat++) {
        if (mat) __syncthreads();           // protect Wlds from previous reads
        // ---- stage this mat's W fragment-blocks (each wave stages NFB/4) ----
        #pragma unroll
        for (int it = 0; it < NFB / 4; it++) {
            int fb   = it * 4 + wv;
            int hsel = fb & 1;
            int rest = fb >> 1;             // ft*NCH + c
            int c    = rest & (NCH - 1);
            int ft   = rest / NCH;
            const unsigned short* src = hsel ? wlo : whi;
            size_t goff = (size_t)(mat * 64 + ft * 16 + lr) * K + c * 32 + lg * 8;
            uint4 d = *(const uint4*)&src[goff];
            *(uint4*)&Wlds[fb * 512 + l * 8] = d;
        }
        __syncthreads();

        #pragma unroll
        for (int ft = 0; ft < 4; ft++) {
            f32x4 acc = {0.f, 0.f, 0.f, 0.f};
            #pragma unroll
            for (int c = 0; c < NCH; c++) {
                const int fb = (ft * NCH + c) << 1;
                bf16x8 Whi = *(const bf16x8*)&Wlds[fb * 512 + l * 8];
                bf16x8 Wlo = *(const bf16x8*)&Wlds[(fb + 1) * 512 + l * 8];
                acc = __builtin_amdgcn_mfma_f32_16x16x32_bf16(Whi, Xhi[c], acc, 0, 0, 0);
                acc = __builtin_amdgcn_mfma_f32_16x16x32_bf16(Wlo, Xhi[c], acc, 0, 0, 0);
                acc = __builtin_amdgcn_mfma_f32_16x16x32_bf16(Whi, Xlo[c], acc, 0, 0, 0);
            }
            if (nok) {
                float4 b4 = *(const float4*)&Bm[mat][ft * 16 + lg * 4];
                float v0 = acc[0] + b4.x;
                float v1 = acc[1] + b4.y;
                float v2 = acc[2] + b4.z;
                float v3 = acc[3] + b4.w;
                size_t off = (size_t)node * HDIM + ft * 16 + lg * 4;
                if (mat == 0) {
                    *(float4*)&q[off] = make_float4(v0, v1, v2, v3);
                } else if (mat == 3) {
                    *(float4*)&sk[off] = make_float4(v0, v1, v2, v3);
                } else {
                    uint2 p;
                    p.x = pack2bf(v0, v1);
                    p.y = pack2bf(v2, v3);
                    if (mat == 1) *(uint2*)&k16[off] = p;
                    else          *(uint2*)&v16[off] = p;
                }
            }
        }
    }
}

// ---------- CSR build, stage 1: per-bucket edge counts (LDS hist only) ----------
__global__ __launch_bounds__(256) void count_bucket(
    const int* __restrict__ ei, int* __restrict__ bcnt)
{
    __shared__ int hist[NBUCK];
    for (int i = threadIdx.x; i < NBUCK; i += 256) hist[i] = 0;
    __syncthreads();
    int e0 = blockIdx.x * EW_CHUNK;
    #pragma unroll
    for (int i = 0; i < EW_CHUNK / 256; i++) {
        int e = e0 + i * 256 + threadIdx.x;
        if (e < N_EDGES) atomicAdd(&hist[ei[N_EDGES + e] >> BSHIFT], 1);
    }
    __syncthreads();
    for (int i = threadIdx.x; i < NBUCK; i += 256)
        if (hist[i]) atomicAdd(&bcnt[i], hist[i]);
}

// ---------- CSR build, stage 2: bucket base scan (196 values, one block) ----------
__global__ __launch_bounds__(256) void scan_bucket(
    const int* __restrict__ bcnt, int* __restrict__ bbase, int* __restrict__ gcursor)
{
    __shared__ int sh[256];
    int t = threadIdx.x;
    int v = (t < NBUCK) ? bcnt[t] : 0;
    sh[t] = v;
    __syncthreads();
    for (int off = 1; off < 256; off <<= 1) {
        int u = (t >= off) ? sh[t - off] : 0;
        __syncthreads();
        sh[t] += u;
        __syncthreads();
    }
    if (t < NBUCK) { bbase[t] = sh[t] - v; gcursor[t] = sh[t] - v; }
}

// ---------- CSR build, stage 3: scatter packed edges into bucket order ----------
// packed entry: (dst_local << 17) | src
__global__ __launch_bounds__(256) void bucket_scatter(
    const int* __restrict__ ei, int* __restrict__ gcursor, int* __restrict__ bedge)
{
    __shared__ int hist[NBUCK];
    __shared__ int base[NBUCK];
    for (int i = threadIdx.x; i < NBUCK; i += 256) hist[i] = 0;
    __syncthreads();
    int e0 = blockIdx.x * EW_CHUNK;
    #pragma unroll
    for (int i = 0; i < EW_CHUNK / 256; i++) {
        int e = e0 + i * 256 + threadIdx.x;
        if (e < N_EDGES) atomicAdd(&hist[ei[N_EDGES + e] >> BSHIFT], 1);
    }
    __syncthreads();
    for (int i = threadIdx.x; i < NBUCK; i += 256)
        base[i] = hist[i] ? atomicAdd(&gcursor[i], hist[i]) : 0;
    __syncthreads();
    for (int i = threadIdx.x; i < NBUCK; i += 256) hist[i] = 0;
    __syncthreads();
    #pragma unroll
    for (int i = 0; i < EW_CHUNK / 256; i++) {
        int e = e0 + i * 256 + threadIdx.x;
        if (e < N_EDGES) {
            int src = ei[e];
            int dst = ei[N_EDGES + e];
            int b = dst >> BSHIFT;
            int pos = base[b] + atomicAdd(&hist[b], 1);
            bedge[pos] = ((dst & (BUCKET_NODES - 1)) << 17) | src;
        }
    }
}

// ---------- CSR build, stage 4: one WG per bucket ----------
__global__ __launch_bounds__(256) void csr_from_buckets(
    const int* __restrict__ bedge, const int* __restrict__ bbase,
    const int* __restrict__ bcnt, int* __restrict__ row_ptr,
    int* __restrict__ csr_src)
{
    __shared__ int cur[BUCKET_NODES];   // 512
    __shared__ int psum[256];
    const int b = blockIdx.x;
    const int dst0 = b << BSHIFT;
    const int t = threadIdx.x;

    for (int i = t; i < BUCKET_NODES; i += 256) cur[i] = 0;
    __syncthreads();

    const int beg = bbase[b], cnt = bcnt[b];
    for (int i = t; i < cnt; i += 256)
        atomicAdd(&cur[bedge[beg + i] >> 17], 1);
    __syncthreads();

    int a0 = cur[2 * t], a1 = cur[2 * t + 1];
    int pair = a0 + a1;
    psum[t] = pair;
    __syncthreads();
    for (int off = 1; off < 256; off <<= 1) {
        int u = (t >= off) ? psum[t - off] : 0;
        __syncthreads();
        psum[t] += u;
        __syncthreads();
    }
    int ex = psum[t] - pair;            // exclusive prefix of this pair

    int d0 = dst0 + 2 * t, d1 = d0 + 1;
    int g0 = beg + ex, g1 = beg + ex + a0;
    if (d0 < N_NODES) row_ptr[d0] = g0;
    if (d1 < N_NODES) row_ptr[d1] = g1;
    if (b == gridDim.x - 1 && t == 255) row_ptr[N_NODES] = beg + psum[255];
    cur[2 * t] = g0;
    cur[2 * t + 1] = g1;
    __syncthreads();

    for (int i = t; i < cnt; i += 256) {
        int ed = bedge[beg + i];
        int pos = atomicAdd(&cur[ed >> 17], 1);
        csr_src[pos] = ed & 0x1FFFF;
    }
}

// ---------- fused attention: wave per dst, 8 edges/iter, bf16 k/v gathers ----------
__global__ __launch_bounds__(256) void attn_fused(
    const int* __restrict__ row_ptr, const int* __restrict__ csr_src,
    const float* __restrict__ q, const unsigned short* __restrict__ k16,
    const unsigned short* __restrict__ v16, const float* __restrict__ skip,
    float* __restrict__ hout, int do_relu)
{
    int n = blockIdx.x * 4 + (threadIdx.x >> 6);
    if (n >= N_NODES) return;
    int lane = threadIdx.x & 63;
    int g = lane >> 3;
    int t = lane & 7;
    int beg = row_ptr[n], end = row_ptr[n + 1];

    const float* qrow = &q[(size_t)n * HDIM + t * 8];
    float4 qa = *(const float4*)qrow;
    float4 qb = *(const float4*)(qrow + 4);
    float m = -1e30f, s = 0.f;
    float4 aca = make_float4(0.f, 0.f, 0.f, 0.f);
    float4 acb = make_float4(0.f, 0.f, 0.f, 0.f);

    for (int i = beg; i < end; i += 8) {
        int e = i + g;
        bool valid = (e < end);
        int src = csr_src[valid ? e : beg];
        uint4 ku = *(const uint4*)&k16[(size_t)src * HDIM + t * 8];
        uint4 vu = *(const uint4*)&v16[(size_t)src * HDIM + t * 8];
        float p = qa.x * __uint_as_float(ku.x << 16)
                + qa.y * __uint_as_float(ku.x & 0xFFFF0000u)
                + qa.z * __uint_as_float(ku.y << 16)
                + qa.w * __uint_as_float(ku.y & 0xFFFF0000u)
                + qb.x * __uint_as_float(ku.z << 16)
                + qb.y * __uint_as_float(ku.z & 0xFFFF0000u)
                + qb.z * __uint_as_float(ku.w << 16)
                + qb.w * __uint_as_float(ku.w & 0xFFFF0000u);
        p += __shfl_xor(p, 1, 64);
        p += __shfl_xor(p, 2, 64);
        p += __shfl_xor(p, 4, 64);
        float a = valid ? p * 0.125f : -INFINITY;
        float mn = fmaxf(m, a);
        float sc = __expf(m - mn);
        float ew = __expf(a - mn);
        s = s * sc + ew;
        aca.x = aca.x * sc + ew * __uint_as_float(vu.x << 16);
        aca.y = aca.y * sc + ew * __uint_as_float(vu.x & 0xFFFF0000u);
        aca.z = aca.z * sc + ew * __uint_as_float(vu.y << 16);
        aca.w = aca.w * sc + ew * __uint_as_float(vu.y & 0xFFFF0000u);
        acb.x = acb.x * sc + ew * __uint_as_float(vu.z << 16);
        acb.y = acb.y * sc + ew * __uint_as_float(vu.z & 0xFFFF0000u);
        acb.z = acb.z * sc + ew * __uint_as_float(vu.w << 16);
        acb.w = acb.w * sc + ew * __uint_as_float(vu.w & 0xFFFF0000u);
        m = mn;
    }

    #pragma unroll
    for (int off = 8; off <= 32; off <<= 1) {
        float m2 = __shfl_xor(m, off, 64);
        float s2 = __shfl_xor(s, off, 64);
        float x0 = __shfl_xor(aca.x, off, 64);
        float x1 = __shfl_xor(aca.y, off, 64);
        float x2 = __shfl_xor(aca.z, off, 64);
        float x3 = __shfl_xor(aca.w, off, 64);
        float x4 = __shfl_xor(acb.x, off, 64);
        float x5 = __shfl_xor(acb.y, off, 64);
        float x6 = __shfl_xor(acb.z, off, 64);
        float x7 = __shfl_xor(acb.w, off, 64);
        float mn = fmaxf(m, m2);
        float c1 = __expf(m - mn);
        float c2 = __expf(m2 - mn);
        s = s * c1 + s2 * c2;
        aca.x = aca.x * c1 + x0 * c2;
        aca.y = aca.y * c1 + x1 * c2;
        aca.z = aca.z * c1 + x2 * c2;
        aca.w = aca.w * c1 + x3 * c2;
        acb.x = acb.x * c1 + x4 * c2;
        acb.y = acb.y * c1 + x5 * c2;
        acb.z = acb.z * c1 + x6 * c2;
        acb.w = acb.w * c1 + x7 * c2;
        m = mn;
    }

    if (g == 0) {
        float inv = (s > 0.f) ? (1.f / s) : 0.f;
        const float* skrow = &skip[(size_t)n * HDIM + t * 8];
        float4 s0 = *(const float4*)skrow;
        float4 s1 = *(const float4*)(skrow + 4);
        float4 o0, o1;
        o0.x = aca.x * inv + s0.x;
        o0.y = aca.y * inv + s0.y;
        o0.z = aca.z * inv + s0.z;
        o0.w = aca.w * inv + s0.w;
        o1.x = acb.x * inv + s1.x;
        o1.y = acb.y * inv + s1.y;
        o1.z = acb.z * inv + s1.z;
        o1.w = acb.w * inv + s1.w;
        if (do_relu) {
            o0.x = fmaxf(o0.x, 0.f); o0.y = fmaxf(o0.y, 0.f);
            o0.z = fmaxf(o0.z, 0.f); o0.w = fmaxf(o0.w, 0.f);
            o1.x = fmaxf(o1.x, 0.f); o1.y = fmaxf(o1.y, 0.f);
            o1.z = fmaxf(o1.z, 0.f); o1.w = fmaxf(o1.w, 0.f);
        }
        float* orow = &hout[(size_t)n * HDIM + t * 8];
        *(float4*)orow = o0;
        *(float4*)(orow + 4) = o1;
    }
}

// ---------- mean pool: run-length accumulate (batch sorted), 64 nodes/wave ----------
__global__ __launch_bounds__(256) void pool_kernel(
    const float* __restrict__ h, const int* __restrict__ batch,
    float* __restrict__ sums, float* __restrict__ cnt)
{
    int wid = blockIdx.x * 4 + (threadIdx.x >> 6);
    int n0 = wid * 64;
    if (n0 >= N_NODES) return;
    int lane = threadIdx.x & 63;
    int nend = min(n0 + 64, N_NODES);
    float acc = 0.f;
    int b_cur = batch[n0];
    int run = 0;
    for (int n = n0; n < nend; n++) {
        int b = batch[n];
        if (b != b_cur) {
            atomicAdd(&sums[b_cur * HDIM + lane], acc);
            if (lane == 0) atomicAdd(&cnt[b_cur], (float)run);
            acc = 0.f; run = 0; b_cur = b;
        }
        acc += h[(size_t)n * HDIM + lane];
        run++;
    }
    atomicAdd(&sums[b_cur * HDIM + lane], acc);
    if (lane == 0) atomicAdd(&cnt[b_cur], (float)run);
}

// ---------- head ----------
__global__ void head_kernel(
    const float* __restrict__ sums, const float* __restrict__ cnt,
    const float* __restrict__ Wl, const float* __restrict__ bl,
    float* __restrict__ out)
{
    int tid = threadIdx.x;
    if (tid >= NB * NC) return;
    int b = tid / NC, c = tid % NC;
    float cc = fmaxf(cnt[b], 1.0f);
    float acc = bl[c];
    #pragma unroll
    for (int f = 0; f < HDIM; f++)
        acc += (sums[b * HDIM + f] / cc) * Wl[c * HDIM + f];
    out[tid] = acc;
}

extern "C" void kernel_launch(void* const* d_in, const int* in_sizes, int n_in,
                              void* d_out, int out_size, void* d_ws, size_t ws_size,
                              hipStream_t stream)
{
    const float* x     = (const float*)d_in[0];
    const int*   ei    = (const int*)d_in[1];
    const int*   batch = (const int*)d_in[2];

    const float* W[3][4];
    const float* B[3][4];
    for (int l = 0; l < 3; l++)
        for (int j = 0; j < 4; j++) {
            W[l][j] = (const float*)d_in[3 + l * 8 + j * 2];
            B[l][j] = (const float*)d_in[3 + l * 8 + j * 2 + 1];
        }
    const float* Wl = (const float*)d_in[27];
    const float* bl = (const float*)d_in[28];
    float* out = (float*)d_out;

    const size_t NF = (size_t)N_NODES * HDIM;
    char* w = (char*)d_ws;
    float*          h       = (float*)w;          w += NF * 4;
    float*          q       = (float*)w;          w += NF * 4;
    unsigned short* k16     = (unsigned short*)w; w += NF * 2;
    unsigned short* v16     = (unsigned short*)w; w += NF * 2;
    float*          skip    = (float*)w;          w += NF * 4;
    int*            csr_src = (int*)w;            w += (size_t)N_EDGES * 4;
    int*            bedge   = (int*)w;            w += (size_t)N_EDGES * 4;
    int*            row_ptr = (int*)w;            w += (size_t)(N_NODES + 1) * 4;
    int*            bcnt    = (int*)w;            w += (size_t)NBUCK * 4;
    int*            bbase   = (int*)w;            w += (size_t)NBUCK * 4;
    int*            gcursor = (int*)w;            w += (size_t)NBUCK * 4;
    float*          sums    = (float*)w;          w += (size_t)NB * HDIM * 4;
    float*          cnt     = (float*)w;          w += (size_t)NB * 4;
    unsigned short* whi[3];
    unsigned short* wlo[3];
    const int wsz[3] = {64 * F_IN, 64 * HDIM, 64 * HDIM};   // per-mat elems
    for (int l = 0; l < 3; l++) {
        whi[l] = (unsigned short*)w; w += (size_t)4 * wsz[l] * 2;
        wlo[l] = (unsigned short*)w; w += (size_t)4 * wsz[l] * 2;
    }

    const int gemm_gx = (N_NODES + 63) / 64;
    const int node_gx = (N_NODES + 3) / 4;
    const int pool_gx = (N_NODES + 64 * 4 - 1) / (64 * 4);

    // ----- W split to bf16 hi/lo (once) -----
    for (int l = 0; l < 3; l++) {
        int n = wsz[l];
        wsplit<<<(4 * n + 255) / 256, 256, 0, stream>>>(
            W[l][0], W[l][1], W[l][2], W[l][3], whi[l], wlo[l], n);
    }

    // ----- CSR build via LDS-staged counting sort (once; shared by all layers) -----
    hipMemsetAsync(bcnt, 0, (size_t)NBUCK * 4, stream);
    count_bucket<<<EW_GRID, 256, 0, stream>>>(ei, bcnt);
    scan_bucket<<<1, 256, 0, stream>>>(bcnt, bbase, gcursor);
    bucket_scatter<<<EW_GRID, 256, 0, stream>>>(ei, gcursor, bedge);
    csr_from_buckets<<<NBUCK, 256, 0, stream>>>(bedge, bbase, bcnt, row_ptr, csr_src);

    for (int l = 0; l < 3; l++) {
        if (l == 0) {
            qkvs_gemm_mfma<F_IN><<<gemm_gx, 256, 0, stream>>>(
                x, whi[0], wlo[0], B[0][0], B[0][1], B[0][2], B[0][3],
                q, k16, v16, skip);
        } else {
            qkvs_gemm_mfma<HDIM><<<gemm_gx, 256, 0, stream>>>(
                h, whi[l], wlo[l], B[l][0], B[l][1], B[l][2], B[l][3],
                q, k16, v16, skip);
        }
        attn_fused<<<node_gx, 256, 0, stream>>>(
            row_ptr, csr_src, q, k16, v16, skip, h, l < 2 ? 1 : 0);
    }

    hipMemsetAsync(sums, 0, (size_t)NB * HDIM * 4, stream);
    hipMemsetAsync(cnt,  0, (size_t)NB * 4, stream);
    pool_kernel<<<pool_gx, 256, 0, stream>>>(h, batch, sums, cnt);
    head_kernel<<<1, 640, 0, stream>>>(sums, cnt, Wl, bl, out);
}

// Round 19
// 443.424 us; speedup vs baseline: 1.2035x; 1.0033x over previous
//
#include <hip/hip_runtime.h>
#include <math.h>

#define N_NODES 100000
#define N_EDGES 1600000
#define NB 64
#define F_IN 128
#define HDIM 64
#define NC 10

#define BSHIFT 9
#define BUCKET_NODES (1 << BSHIFT)                          // 512
#define NBUCK ((N_NODES + BUCKET_NODES - 1) >> BSHIFT)      // 196
#define EW_CHUNK 4096
#define EW_GRID ((N_EDGES + EW_CHUNK - 1) / EW_CHUNK)       // 391

typedef __attribute__((ext_vector_type(8))) short bf16x8;
typedef __attribute__((ext_vector_type(4))) float f32x4;
typedef _Float16 f16x2 __attribute__((ext_vector_type(2)));

// ---------- bf16 helpers (GEMM compute path) ----------
__device__ __forceinline__ unsigned short f2bf(float f) {
    unsigned u = __float_as_uint(f);
    u += 0x7FFFu + ((u >> 16) & 1u);    // round to nearest even
    return (unsigned short)(u >> 16);
}
__device__ __forceinline__ float bf2f(unsigned short b) {
    return __uint_as_float((unsigned)b << 16);
}

// ---------- fp16 helpers (k/v storage) ----------
__device__ __forceinline__ unsigned pack2h(float a, float b) {
    union { f16x2 h; unsigned u; } c;
    c.h[0] = (_Float16)a;
    c.h[1] = (_Float16)b;
    return c.u;
}
__device__ __forceinline__ f16x2 as_h2(unsigned u) {
    union { unsigned u; f16x2 h; } c;
    c.u = u;
    return c.h;
}
__device__ __forceinline__ unsigned h2_as_u(f16x2 h) {
    union { f16x2 h; unsigned u; } c;
    c.h = h;
    return c.u;
}

// ---------- W split: W -> bf16 hi + bf16 lo (residual) ----------
__global__ __launch_bounds__(256) void wsplit(
    const float* __restrict__ W0, const float* __restrict__ W1,
    const float* __restrict__ W2, const float* __restrict__ W3,
    unsigned short* __restrict__ hi, unsigned short* __restrict__ lo, int n)
{
    int i = blockIdx.x * 256 + threadIdx.x;
    if (i >= 4 * n) return;
    const float* Ws[4] = {W0, W1, W2, W3};
    float w = Ws[i / n][i % n];
    unsigned short h = f2bf(w);
    hi[i] = h;
    lo[i] = f2bf(w - bf2f(h));
}

// ---------- fused q/k/v/skip GEMM via MFMA, OPERAND-SWAPPED ----------
// D = W·X^T: A = W fragment (LDS, per mat), B = X fragment (regs).
// D: col = node (lane&15), row = feat (lg*4+i) -> vector stores (r18 win).
// k/v emitted as FP16 (e5m10: more precise than bf16, same bytes).
template<int K>
__global__ __launch_bounds__(256) void qkvs_gemm_mfma(
    const float* __restrict__ xin,
    const unsigned short* __restrict__ whi,
    const unsigned short* __restrict__ wlo,
    const float* __restrict__ bq, const float* __restrict__ bk,
    const float* __restrict__ bv, const float* __restrict__ bs,
    float* __restrict__ q, unsigned short* __restrict__ k16,
    unsigned short* __restrict__ v16, float* __restrict__ sk)
{
    constexpr int NCH = K / 32;
    constexpr int NFB = 4 * NCH * 2;        // per-mat: feat-tiles * chunks * (hi,lo)
    __shared__ short Wlds[NFB * 512];       // 1 KB per fragment-block

    const int tid = threadIdx.x;
    const int wv  = tid >> 6;
    const int l   = tid & 63;
    const int lr  = l & 15;      // B-col (node) / A-row (feat) / D-col (node)
    const int lg  = l >> 4;      // k-group (8 consecutive k); D-row group
    const int n0  = blockIdx.x * 64 + wv * 16;
    const int node = n0 + lr;
    const bool nok = node < N_NODES;

    // ---- load this wave's 16 X rows, split into bf16 hi/lo B-fragments ----
    bf16x8 Xhi[NCH], Xlo[NCH];
    {
        const float* xr = xin + (size_t)(nok ? node : 0) * K + lg * 8;
        #pragma unroll
        for (int c = 0; c < NCH; c++) {
            float4 f0, f1;
            if (nok) {
                f0 = *(const float4*)(xr + c * 32);
                f1 = *(const float4*)(xr + c * 32 + 4);
            } else {
                f0 = make_float4(0.f, 0.f, 0.f, 0.f);
                f1 = f0;
            }
            float xv[8] = {f0.x, f0.y, f0.z, f0.w, f1.x, f1.y, f1.z, f1.w};
            #pragma unroll
            for (int j = 0; j < 8; j++) {
                unsigned short hb = f2bf(xv[j]);
                Xhi[c][j] = (short)hb;
                Xlo[c][j] = (short)f2bf(xv[j] - bf2f(hb));
            }
        }
    }

    const float* Bm[4] = {bq, bk, bv, bs};

    for (int mat = 0; mat < 4; mat++) {
        if (mat) __syncthreads();           // protect Wlds from previous reads
        #pragma unroll
        for (int it = 0; it < NFB / 4; it++) {
            int fb   = it * 4 + wv;
            int hsel = fb & 1;
            int rest = fb >> 1;             // ft*NCH + c
            int c    = rest & (NCH - 1);
            int ft   = rest / NCH;
            const unsigned short* src = hsel ? wlo : whi;
            size_t goff = (size_t)(mat * 64 + ft * 16 + lr) * K + c * 32 + lg * 8;
            uint4 d = *(const uint4*)&src[goff];
            *(uint4*)&Wlds[fb * 512 + l * 8] = d;
        }
        __syncthreads();

        #pragma unroll
        for (int ft = 0; ft < 4; ft++) {
            f32x4 acc = {0.f, 0.f, 0.f, 0.f};
            #pragma unroll
            for (int c = 0; c < NCH; c++) {
                const int fb = (ft * NCH + c) << 1;
                bf16x8 Whi = *(const bf16x8*)&Wlds[fb * 512 + l * 8];
                bf16x8 Wlo = *(const bf16x8*)&Wlds[(fb + 1) * 512 + l * 8];
                acc = __builtin_amdgcn_mfma_f32_16x16x32_bf16(Whi, Xhi[c], acc, 0, 0, 0);
                acc = __builtin_amdgcn_mfma_f32_16x16x32_bf16(Wlo, Xhi[c], acc, 0, 0, 0);
                acc = __builtin_amdgcn_mfma_f32_16x16x32_bf16(Whi, Xlo[c], acc, 0, 0, 0);
            }
            if (nok) {
                float4 b4 = *(const float4*)&Bm[mat][ft * 16 + lg * 4];
                float v0 = acc[0] + b4.x;
                float v1 = acc[1] + b4.y;
                float v2 = acc[2] + b4.z;
                float v3 = acc[3] + b4.w;
                size_t off = (size_t)node * HDIM + ft * 16 + lg * 4;
                if (mat == 0) {
                    *(float4*)&q[off] = make_float4(v0, v1, v2, v3);
                } else if (mat == 3) {
                    *(float4*)&sk[off] = make_float4(v0, v1, v2, v3);
                } else {
                    uint2 p;
                    p.x = pack2h(v0, v1);
                    p.y = pack2h(v2, v3);
                    if (mat == 1) *(uint2*)&k16[off] = p;
                    else          *(uint2*)&v16[off] = p;
                }
            }
        }
    }
}

// ---------- CSR build, stage 1: per-bucket edge counts (LDS hist only) ----------
__global__ __launch_bounds__(256) void count_bucket(
    const int* __restrict__ ei, int* __restrict__ bcnt)
{
    __shared__ int hist[NBUCK];
    for (int i = threadIdx.x; i < NBUCK; i += 256) hist[i] = 0;
    __syncthreads();
    int e0 = blockIdx.x * EW_CHUNK;
    #pragma unroll
    for (int i = 0; i < EW_CHUNK / 256; i++) {
        int e = e0 + i * 256 + threadIdx.x;
        if (e < N_EDGES) atomicAdd(&hist[ei[N_EDGES + e] >> BSHIFT], 1);
    }
    __syncthreads();
    for (int i = threadIdx.x; i < NBUCK; i += 256)
        if (hist[i]) atomicAdd(&bcnt[i], hist[i]);
}

// ---------- CSR build, stage 2: bucket base scan (196 values, one block) ----------
__global__ __launch_bounds__(256) void scan_bucket(
    const int* __restrict__ bcnt, int* __restrict__ bbase, int* __restrict__ gcursor)
{
    __shared__ int sh[256];
    int t = threadIdx.x;
    int v = (t < NBUCK) ? bcnt[t] : 0;
    sh[t] = v;
    __syncthreads();
    for (int off = 1; off < 256; off <<= 1) {
        int u = (t >= off) ? sh[t - off] : 0;
        __syncthreads();
        sh[t] += u;
        __syncthreads();
    }
    if (t < NBUCK) { bbase[t] = sh[t] - v; gcursor[t] = sh[t] - v; }
}

// ---------- CSR build, stage 3: scatter packed edges into bucket order ----------
// packed entry: (dst_local << 17) | src
__global__ __launch_bounds__(256) void bucket_scatter(
    const int* __restrict__ ei, int* __restrict__ gcursor, int* __restrict__ bedge)
{
    __shared__ int hist[NBUCK];
    __shared__ int base[NBUCK];
    for (int i = threadIdx.x; i < NBUCK; i += 256) hist[i] = 0;
    __syncthreads();
    int e0 = blockIdx.x * EW_CHUNK;
    #pragma unroll
    for (int i = 0; i < EW_CHUNK / 256; i++) {
        int e = e0 + i * 256 + threadIdx.x;
        if (e < N_EDGES) atomicAdd(&hist[ei[N_EDGES + e] >> BSHIFT], 1);
    }
    __syncthreads();
    for (int i = threadIdx.x; i < NBUCK; i += 256)
        base[i] = hist[i] ? atomicAdd(&gcursor[i], hist[i]) : 0;
    __syncthreads();
    for (int i = threadIdx.x; i < NBUCK; i += 256) hist[i] = 0;
    __syncthreads();
    #pragma unroll
    for (int i = 0; i < EW_CHUNK / 256; i++) {
        int e = e0 + i * 256 + threadIdx.x;
        if (e < N_EDGES) {
            int src = ei[e];
            int dst = ei[N_EDGES + e];
            int b = dst >> BSHIFT;
            int pos = base[b] + atomicAdd(&hist[b], 1);
            bedge[pos] = ((dst & (BUCKET_NODES - 1)) << 17) | src;
        }
    }
}

// ---------- CSR build, stage 4: one WG per bucket ----------
__global__ __launch_bounds__(256) void csr_from_buckets(
    const int* __restrict__ bedge, const int* __restrict__ bbase,
    const int* __restrict__ bcnt, int* __restrict__ row_ptr,
    int* __restrict__ csr_src)
{
    __shared__ int cur[BUCKET_NODES];   // 512
    __shared__ int psum[256];
    const int b = blockIdx.x;
    const int dst0 = b << BSHIFT;
    const int t = threadIdx.x;

    for (int i = t; i < BUCKET_NODES; i += 256) cur[i] = 0;
    __syncthreads();

    const int beg = bbase[b], cnt = bcnt[b];
    for (int i = t; i < cnt; i += 256)
        atomicAdd(&cur[bedge[beg + i] >> 17], 1);
    __syncthreads();

    int a0 = cur[2 * t], a1 = cur[2 * t + 1];
    int pair = a0 + a1;
    psum[t] = pair;
    __syncthreads();
    for (int off = 1; off < 256; off <<= 1) {
        int u = (t >= off) ? psum[t - off] : 0;
        __syncthreads();
        psum[t] += u;
        __syncthreads();
    }
    int ex = psum[t] - pair;            // exclusive prefix of this pair

    int d0 = dst0 + 2 * t, d1 = d0 + 1;
    int g0 = beg + ex, g1 = beg + ex + a0;
    if (d0 < N_NODES) row_ptr[d0] = g0;
    if (d1 < N_NODES) row_ptr[d1] = g1;
    if (b == gridDim.x - 1 && t == 255) row_ptr[N_NODES] = beg + psum[255];
    cur[2 * t] = g0;
    cur[2 * t + 1] = g1;
    __syncthreads();

    for (int i = t; i < cnt; i += 256) {
        int ed = bedge[beg + i];
        int pos = atomicAdd(&cur[ed >> 17], 1);
        csr_src[pos] = ed & 0x1FFFF;
    }
}

// ---------- fused attention: wave per dst, 8 edges/iter, fp16 k/v + dot2 ----------
// lane = g*8 + t : g = edge slot (0..7), t = feature octet (features 8t..8t+7)
__global__ __launch_bounds__(256) void attn_fused(
    const int* __restrict__ row_ptr, const int* __restrict__ csr_src,
    const float* __restrict__ q, const unsigned short* __restrict__ k16,
    const unsigned short* __restrict__ v16, const float* __restrict__ skip,
    float* __restrict__ hout, int do_relu)
{
    int n = blockIdx.x * 4 + (threadIdx.x >> 6);
    if (n >= N_NODES) return;
    int lane = threadIdx.x & 63;
    int g = lane >> 3;
    int t = lane & 7;
    int beg = row_ptr[n], end = row_ptr[n + 1];

    // q as 4x half2
    f16x2 qh[4];
    {
        const float* qrow = &q[(size_t)n * HDIM + t * 8];
        float4 f0 = *(const float4*)qrow;
        float4 f1 = *(const float4*)(qrow + 4);
        qh[0][0] = (_Float16)f0.x; qh[0][1] = (_Float16)f0.y;
        qh[1][0] = (_Float16)f0.z; qh[1][1] = (_Float16)f0.w;
        qh[2][0] = (_Float16)f1.x; qh[2][1] = (_Float16)f1.y;
        qh[3][0] = (_Float16)f1.z; qh[3][1] = (_Float16)f1.w;
    }

    float m = -1e30f, s = 0.f;
    f16x2 acc0 = {(_Float16)0.f, (_Float16)0.f};
    f16x2 acc1 = acc0, acc2 = acc0, acc3 = acc0;

    for (int i = beg; i < end; i += 8) {
        int e = i + g;
        bool valid = (e < end);
        int src = csr_src[valid ? e : beg];
        uint4 ku = *(const uint4*)&k16[(size_t)src * HDIM + t * 8];
        uint4 vu = *(const uint4*)&v16[(size_t)src * HDIM + t * 8];
        float p;
#if __has_builtin(__builtin_amdgcn_fdot2)
        p = __builtin_amdgcn_fdot2(qh[0], as_h2(ku.x), 0.f, false);
        p = __builtin_amdgcn_fdot2(qh[1], as_h2(ku.y), p, false);
        p = __builtin_amdgcn_fdot2(qh[2], as_h2(ku.z), p, false);
        p = __builtin_amdgcn_fdot2(qh[3], as_h2(ku.w), p, false);
#else
        {
            f16x2 k0 = as_h2(ku.x), k1 = as_h2(ku.y), k2 = as_h2(ku.z), k3 = as_h2(ku.w);
            p = (float)qh[0][0]*(float)k0[0] + (float)qh[0][1]*(float)k0[1]
              + (float)qh[1][0]*(float)k1[0] + (float)qh[1][1]*(float)k1[1]
              + (float)qh[2][0]*(float)k2[0] + (float)qh[2][1]*(float)k2[1]
              + (float)qh[3][0]*(float)k3[0] + (float)qh[3][1]*(float)k3[1];
        }
#endif
        p += __shfl_xor(p, 1, 64);
        p += __shfl_xor(p, 2, 64);
        p += __shfl_xor(p, 4, 64);
        float a = valid ? p * 0.125f : -INFINITY;
        float mn = fmaxf(m, a);
        float sc = __expf(m - mn);
        float ew = __expf(a - mn);
        s = s * sc + ew;
        m = mn;
        _Float16 sch = (_Float16)sc, ewh = (_Float16)ew;
        f16x2 sc2 = {sch, sch}, ew2 = {ewh, ewh};
        acc0 = acc0 * sc2 + as_h2(vu.x) * ew2;
        acc1 = acc1 * sc2 + as_h2(vu.y) * ew2;
        acc2 = acc2 * sc2 + as_h2(vu.z) * ew2;
        acc3 = acc3 * sc2 + as_h2(vu.w) * ew2;
    }

    // merge the 8 group-local softmax states (offsets 8,16,32)
    #pragma unroll
    for (int off = 8; off <= 32; off <<= 1) {
        float m2 = __shfl_xor(m, off, 64);
        float s2 = __shfl_xor(s, off, 64);
        int w0 = __shfl_xor((int)h2_as_u(acc0), off, 64);
        int w1 = __shfl_xor((int)h2_as_u(acc1), off, 64);
        int w2 = __shfl_xor((int)h2_as_u(acc2), off, 64);
        int w3 = __shfl_xor((int)h2_as_u(acc3), off, 64);
        float mn = fmaxf(m, m2);
        float c1 = __expf(m - mn);
        float c2 = __expf(m2 - mn);
        s = s * c1 + s2 * c2;
        m = mn;
        _Float16 c1h = (_Float16)c1, c2h = (_Float16)c2;
        f16x2 c12 = {c1h, c1h}, c22 = {c2h, c2h};
        acc0 = acc0 * c12 + as_h2((unsigned)w0) * c22;
        acc1 = acc1 * c12 + as_h2((unsigned)w1) * c22;
        acc2 = acc2 * c12 + as_h2((unsigned)w2) * c22;
        acc3 = acc3 * c12 + as_h2((unsigned)w3) * c22;
    }

    if (g == 0) {
        float inv = (s > 0.f) ? (1.f / s) : 0.f;
        const float* skrow = &skip[(size_t)n * HDIM + t * 8];
        float4 s0 = *(const float4*)skrow;
        float4 s1 = *(const float4*)(skrow + 4);
        float4 o0, o1;
        o0.x = (float)acc0[0] * inv + s0.x;
        o0.y = (float)acc0[1] * inv + s0.y;
        o0.z = (float)acc1[0] * inv + s0.z;
        o0.w = (float)acc1[1] * inv + s0.w;
        o1.x = (float)acc2[0] * inv + s1.x;
        o1.y = (float)acc2[1] * inv + s1.y;
        o1.z = (float)acc3[0] * inv + s1.z;
        o1.w = (float)acc3[1] * inv + s1.w;
        if (do_relu) {
            o0.x = fmaxf(o0.x, 0.f); o0.y = fmaxf(o0.y, 0.f);
            o0.z = fmaxf(o0.z, 0.f); o0.w = fmaxf(o0.w, 0.f);
            o1.x = fmaxf(o1.x, 0.f); o1.y = fmaxf(o1.y, 0.f);
            o1.z = fmaxf(o1.z, 0.f); o1.w = fmaxf(o1.w, 0.f);
        }
        float* orow = &hout[(size_t)n * HDIM + t * 8];
        *(float4*)orow = o0;
        *(float4*)(orow + 4) = o1;
    }
}

// ---------- mean pool: run-length accumulate (batch sorted), 64 nodes/wave ----------
__global__ __launch_bounds__(256) void pool_kernel(
    const float* __restrict__ h, const int* __restrict__ batch,
    float* __restrict__ sums, float* __restrict__ cnt)
{
    int wid = blockIdx.x * 4 + (threadIdx.x >> 6);
    int n0 = wid * 64;
    if (n0 >= N_NODES) return;
    int lane = threadIdx.x & 63;
    int nend = min(n0 + 64, N_NODES);
    float acc = 0.f;
    int b_cur = batch[n0];
    int run = 0;
    for (int n = n0; n < nend; n++) {
        int b = batch[n];
        if (b != b_cur) {
            atomicAdd(&sums[b_cur * HDIM + lane], acc);
            if (lane == 0) atomicAdd(&cnt[b_cur], (float)run);
            acc = 0.f; run = 0; b_cur = b;
        }
        acc += h[(size_t)n * HDIM + lane];
        run++;
    }
    atomicAdd(&sums[b_cur * HDIM + lane], acc);
    if (lane == 0) atomicAdd(&cnt[b_cur], (float)run);
}

// ---------- head ----------
__global__ void head_kernel(
    const float* __restrict__ sums, const float* __restrict__ cnt,
    const float* __restrict__ Wl, const float* __restrict__ bl,
    float* __restrict__ out)
{
    int tid = threadIdx.x;
    if (tid >= NB * NC) return;
    int b = tid / NC, c = tid % NC;
    float cc = fmaxf(cnt[b], 1.0f);
    float acc = bl[c];
    #pragma unroll
    for (int f = 0; f < HDIM; f++)
        acc += (sums[b * HDIM + f] / cc) * Wl[c * HDIM + f];
    out[tid] = acc;
}

extern "C" void kernel_launch(void* const* d_in, const int* in_sizes, int n_in,
                              void* d_out, int out_size, void* d_ws, size_t ws_size,
                              hipStream_t stream)
{
    const float* x     = (const float*)d_in[0];
    const int*   ei    = (const int*)d_in[1];
    const int*   batch = (const int*)d_in[2];

    const float* W[3][4];
    const float* B[3][4];
    for (int l = 0; l < 3; l++)
        for (int j = 0; j < 4; j++) {
            W[l][j] = (const float*)d_in[3 + l * 8 + j * 2];
            B[l][j] = (const float*)d_in[3 + l * 8 + j * 2 + 1];
        }
    const float* Wl = (const float*)d_in[27];
    const float* bl = (const float*)d_in[28];
    float* out = (float*)d_out;

    const size_t NF = (size_t)N_NODES * HDIM;
    char* w = (char*)d_ws;
    float*          h       = (float*)w;          w += NF * 4;
    float*          q       = (float*)w;          w += NF * 4;
    unsigned short* k16     = (unsigned short*)w; w += NF * 2;
    unsigned short* v16     = (unsigned short*)w; w += NF * 2;
    float*          skip    = (float*)w;          w += NF * 4;
    int*            csr_src = (int*)w;            w += (size_t)N_EDGES * 4;
    int*            bedge   = (int*)w;            w += (size_t)N_EDGES * 4;
    int*            row_ptr = (int*)w;            w += (size_t)(N_NODES + 1) * 4;
    int*            bcnt    = (int*)w;            w += (size_t)NBUCK * 4;
    int*            bbase   = (int*)w;            w += (size_t)NBUCK * 4;
    int*            gcursor = (int*)w;            w += (size_t)NBUCK * 4;
    float*          sums    = (float*)w;          w += (size_t)NB * HDIM * 4;
    float*          cnt     = (float*)w;          w += (size_t)NB * 4;
    unsigned short* whi[3];
    unsigned short* wlo[3];
    const int wsz[3] = {64 * F_IN, 64 * HDIM, 64 * HDIM};   // per-mat elems
    for (int l = 0; l < 3; l++) {
        whi[l] = (unsigned short*)w; w += (size_t)4 * wsz[l] * 2;
        wlo[l] = (unsigned short*)w; w += (size_t)4 * wsz[l] * 2;
    }

    const int gemm_gx = (N_NODES + 63) / 64;
    const int node_gx = (N_NODES + 3) / 4;
    const int pool_gx = (N_NODES + 64 * 4 - 1) / (64 * 4);

    // ----- W split to bf16 hi/lo (once) -----
    for (int l = 0; l < 3; l++) {
        int n = wsz[l];
        wsplit<<<(4 * n + 255) / 256, 256, 0, stream>>>(
            W[l][0], W[l][1], W[l][2], W[l][3], whi[l], wlo[l], n);
    }

    // ----- CSR build via LDS-staged counting sort (once; shared by all layers) -----
    hipMemsetAsync(bcnt, 0, (size_t)NBUCK * 4, stream);
    count_bucket<<<EW_GRID, 256, 0, stream>>>(ei, bcnt);
    scan_bucket<<<1, 256, 0, stream>>>(bcnt, bbase, gcursor);
    bucket_scatter<<<EW_GRID, 256, 0, stream>>>(ei, gcursor, bedge);
    csr_from_buckets<<<NBUCK, 256, 0, stream>>>(bedge, bbase, bcnt, row_ptr, csr_src);

    for (int l = 0; l < 3; l++) {
        if (l == 0) {
            qkvs_gemm_mfma<F_IN><<<gemm_gx, 256, 0, stream>>>(
                x, whi[0], wlo[0], B[0][0], B[0][1], B[0][2], B[0][3],
                q, k16, v16, skip);
        } else {
            qkvs_gemm_mfma<HDIM><<<gemm_gx, 256, 0, stream>>>(
                h, whi[l], wlo[l], B[l][0], B[l][1], B[l][2], B[l][3],
                q, k16, v16, skip);
        }
        attn_fused<<<node_gx, 256, 0, stream>>>(
            row_ptr, csr_src, q, k16, v16, skip, h, l < 2 ? 1 : 0);
    }

    hipMemsetAsync(sums, 0, (size_t)NB * HDIM * 4, stream);
    hipMemsetAsync(cnt,  0, (size_t)NB * 4, stream);
    pool_kernel<<<pool_gx, 256, 0, stream>>>(h, batch, sums, cnt);
    head_kernel<<<1, 640, 0, stream>>>(sums, cnt, Wl, bl, out);
}

// Round 20
// 411.888 us; speedup vs baseline: 1.2956x; 1.0766x over previous
//
#include <hip/hip_runtime.h>
#include <math.h>

#define N_NODES 100000
#define N_EDGES 1600000
#define NB 64
#define F_IN 128
#define HDIM 64
#define NC 10

#define BSHIFT 9
#define BUCKET_NODES (1 << BSHIFT)                          // 512
#define NBUCK ((N_NODES + BUCKET_NODES - 1) >> BSHIFT)      // 196
#define BCAP 16384                                          // padded bucket capacity
#define EW_CHUNK 4096
#define EW_GRID ((N_EDGES + EW_CHUNK - 1) / EW_CHUNK)       // 391

typedef __attribute__((ext_vector_type(8))) short bf16x8;
typedef __attribute__((ext_vector_type(4))) float f32x4;
typedef _Float16 f16x2 __attribute__((ext_vector_type(2)));

// ---------- bf16 helpers (GEMM compute path) ----------
__device__ __forceinline__ unsigned short f2bf(float f) {
    unsigned u = __float_as_uint(f);
    u += 0x7FFFu + ((u >> 16) & 1u);    // round to nearest even
    return (unsigned short)(u >> 16);
}
__device__ __forceinline__ float bf2f(unsigned short b) {
    return __uint_as_float((unsigned)b << 16);
}

// ---------- fp16 helpers (k/v storage) ----------
__device__ __forceinline__ unsigned pack2h(float a, float b) {
    union { f16x2 h; unsigned u; } c;
    c.h[0] = (_Float16)a;
    c.h[1] = (_Float16)b;
    return c.u;
}
__device__ __forceinline__ f16x2 as_h2(unsigned u) {
    union { unsigned u; f16x2 h; } c;
    c.u = u;
    return c.h;
}
__device__ __forceinline__ unsigned h2_as_u(f16x2 h) {
    union { f16x2 h; unsigned u; } c;
    c.h = h;
    return c.u;
}

// ---------- W split: W -> bf16 hi + bf16 lo (residual) ----------
__global__ __launch_bounds__(256) void wsplit(
    const float* __restrict__ W0, const float* __restrict__ W1,
    const float* __restrict__ W2, const float* __restrict__ W3,
    unsigned short* __restrict__ hi, unsigned short* __restrict__ lo, int n)
{
    int i = blockIdx.x * 256 + threadIdx.x;
    if (i >= 4 * n) return;
    const float* Ws[4] = {W0, W1, W2, W3};
    float w = Ws[i / n][i % n];
    unsigned short h = f2bf(w);
    hi[i] = h;
    lo[i] = f2bf(w - bf2f(h));
}

// ---------- fused q/k/v/skip GEMM via MFMA, OPERAND-SWAPPED (r18 win) ----------
template<int K>
__global__ __launch_bounds__(256) void qkvs_gemm_mfma(
    const float* __restrict__ xin,
    const unsigned short* __restrict__ whi,
    const unsigned short* __restrict__ wlo,
    const float* __restrict__ bq, const float* __restrict__ bk,
    const float* __restrict__ bv, const float* __restrict__ bs,
    float* __restrict__ q, unsigned short* __restrict__ k16,
    unsigned short* __restrict__ v16, float* __restrict__ sk)
{
    constexpr int NCH = K / 32;
    constexpr int NFB = 4 * NCH * 2;        // per-mat: feat-tiles * chunks * (hi,lo)
    __shared__ short Wlds[NFB * 512];       // 1 KB per fragment-block

    const int tid = threadIdx.x;
    const int wv  = tid >> 6;
    const int l   = tid & 63;
    const int lr  = l & 15;      // B-col (node) / A-row (feat) / D-col (node)
    const int lg  = l >> 4;      // k-group (8 consecutive k); D-row group
    const int n0  = blockIdx.x * 64 + wv * 16;
    const int node = n0 + lr;
    const bool nok = node < N_NODES;

    bf16x8 Xhi[NCH], Xlo[NCH];
    {
        const float* xr = xin + (size_t)(nok ? node : 0) * K + lg * 8;
        #pragma unroll
        for (int c = 0; c < NCH; c++) {
            float4 f0, f1;
            if (nok) {
                f0 = *(const float4*)(xr + c * 32);
                f1 = *(const float4*)(xr + c * 32 + 4);
            } else {
                f0 = make_float4(0.f, 0.f, 0.f, 0.f);
                f1 = f0;
            }
            float xv[8] = {f0.x, f0.y, f0.z, f0.w, f1.x, f1.y, f1.z, f1.w};
            #pragma unroll
            for (int j = 0; j < 8; j++) {
                unsigned short hb = f2bf(xv[j]);
                Xhi[c][j] = (short)hb;
                Xlo[c][j] = (short)f2bf(xv[j] - bf2f(hb));
            }
        }
    }

    const float* Bm[4] = {bq, bk, bv, bs};

    for (int mat = 0; mat < 4; mat++) {
        if (mat) __syncthreads();
        #pragma unroll
        for (int it = 0; it < NFB / 4; it++) {
            int fb   = it * 4 + wv;
            int hsel = fb & 1;
            int rest = fb >> 1;             // ft*NCH + c
            int c    = rest & (NCH - 1);
            int ft   = rest / NCH;
            const unsigned short* src = hsel ? wlo : whi;
            size_t goff = (size_t)(mat * 64 + ft * 16 + lr) * K + c * 32 + lg * 8;
            uint4 d = *(const uint4*)&src[goff];
            *(uint4*)&Wlds[fb * 512 + l * 8] = d;
        }
        __syncthreads();

        #pragma unroll
        for (int ft = 0; ft < 4; ft++) {
            f32x4 acc = {0.f, 0.f, 0.f, 0.f};
            #pragma unroll
            for (int c = 0; c < NCH; c++) {
                const int fb = (ft * NCH + c) << 1;
                bf16x8 Whi = *(const bf16x8*)&Wlds[fb * 512 + l * 8];
                bf16x8 Wlo = *(const bf16x8*)&Wlds[(fb + 1) * 512 + l * 8];
                acc = __builtin_amdgcn_mfma_f32_16x16x32_bf16(Whi, Xhi[c], acc, 0, 0, 0);
                acc = __builtin_amdgcn_mfma_f32_16x16x32_bf16(Wlo, Xhi[c], acc, 0, 0, 0);
                acc = __builtin_amdgcn_mfma_f32_16x16x32_bf16(Whi, Xlo[c], acc, 0, 0, 0);
            }
            if (nok) {
                float4 b4 = *(const float4*)&Bm[mat][ft * 16 + lg * 4];
                float v0 = acc[0] + b4.x;
                float v1 = acc[1] + b4.y;
                float v2 = acc[2] + b4.z;
                float v3 = acc[3] + b4.w;
                size_t off = (size_t)node * HDIM + ft * 16 + lg * 4;
                if (mat == 0) {
                    *(float4*)&q[off] = make_float4(v0, v1, v2, v3);
                } else if (mat == 3) {
                    *(float4*)&sk[off] = make_float4(v0, v1, v2, v3);
                } else {
                    uint2 p;
                    p.x = pack2h(v0, v1);
                    p.y = pack2h(v2, v3);
                    if (mat == 1) *(uint2*)&k16[off] = p;
                    else          *(uint2*)&v16[off] = p;
                }
            }
        }
    }
}

// ---------- CSR build (padded buckets; count/scan kernels eliminated) ----------
__global__ void init_cursor(int* __restrict__ gcursor)
{
    int t = threadIdx.x;
    if (t < NBUCK) gcursor[t] = t * BCAP;
}

// scatter packed edges into padded bucket regions
// packed entry: (dst_local << 17) | src
__global__ __launch_bounds__(256) void bucket_scatter(
    const int* __restrict__ ei, int* __restrict__ gcursor, int* __restrict__ bedge)
{
    __shared__ int hist[NBUCK];
    __shared__ int base[NBUCK];
    for (int i = threadIdx.x; i < NBUCK; i += 256) hist[i] = 0;
    __syncthreads();
    int e0 = blockIdx.x * EW_CHUNK;
    #pragma unroll
    for (int i = 0; i < EW_CHUNK / 256; i++) {
        int e = e0 + i * 256 + threadIdx.x;
        if (e < N_EDGES) atomicAdd(&hist[ei[N_EDGES + e] >> BSHIFT], 1);
    }
    __syncthreads();
    for (int i = threadIdx.x; i < NBUCK; i += 256)
        base[i] = hist[i] ? atomicAdd(&gcursor[i], hist[i]) : 0;
    __syncthreads();
    for (int i = threadIdx.x; i < NBUCK; i += 256) hist[i] = 0;
    __syncthreads();
    #pragma unroll
    for (int i = 0; i < EW_CHUNK / 256; i++) {
        int e = e0 + i * 256 + threadIdx.x;
        if (e < N_EDGES) {
            int src = ei[e];
            int dst = ei[N_EDGES + e];
            int b = dst >> BSHIFT;
            int pos = base[b] + atomicAdd(&hist[b], 1);
            bedge[pos] = ((dst & (BUCKET_NODES - 1)) << 17) | src;
        }
    }
}

// one WG per bucket: LDS hist -> scan -> row_beg/row_end (padded csr) -> place
__global__ __launch_bounds__(256) void csr_from_buckets(
    const int* __restrict__ bedge, const int* __restrict__ gcursor,
    int* __restrict__ row_beg, int* __restrict__ row_end,
    int* __restrict__ csr_src)
{
    __shared__ int cur[BUCKET_NODES];   // 512
    __shared__ int psum[256];
    const int b = blockIdx.x;
    const int dst0 = b << BSHIFT;
    const int t = threadIdx.x;
    const int beg = b * BCAP;
    const int cnt = gcursor[b] - beg;

    for (int i = t; i < BUCKET_NODES; i += 256) cur[i] = 0;
    __syncthreads();

    for (int i = t; i < cnt; i += 256)
        atomicAdd(&cur[bedge[beg + i] >> 17], 1);
    __syncthreads();

    int a0 = cur[2 * t], a1 = cur[2 * t + 1];
    int pair = a0 + a1;
    psum[t] = pair;
    __syncthreads();
    for (int off = 1; off < 256; off <<= 1) {
        int u = (t >= off) ? psum[t - off] : 0;
        __syncthreads();
        psum[t] += u;
        __syncthreads();
    }
    int ex = psum[t] - pair;            // exclusive prefix of this pair

    int d0 = dst0 + 2 * t, d1 = d0 + 1;
    int g0 = beg + ex, g1 = beg + ex + a0;
    if (d0 < N_NODES) { row_beg[d0] = g0; row_end[d0] = g0 + a0; }
    if (d1 < N_NODES) { row_beg[d1] = g1; row_end[d1] = g1 + a1; }
    cur[2 * t] = g0;
    cur[2 * t + 1] = g1;
    __syncthreads();

    for (int i = t; i < cnt; i += 256) {
        int ed = bedge[beg + i];
        int pos = atomicAdd(&cur[ed >> 17], 1);
        csr_src[pos] = ed & 0x1FFFF;
    }
}

// ---------- fused attention: wave per dst, 16 edges/iter (2 indep states) ----------
// lane = g*8 + t : g = edge slot (0..7), t = feature octet (features 8t..8t+7)
__global__ __launch_bounds__(256) void attn_fused(
    const int* __restrict__ row_beg, const int* __restrict__ row_end,
    const int* __restrict__ csr_src,
    const float* __restrict__ q, const unsigned short* __restrict__ k16,
    const unsigned short* __restrict__ v16, const float* __restrict__ skip,
    float* __restrict__ hout, int do_relu)
{
    int n = blockIdx.x * 4 + (threadIdx.x >> 6);
    if (n >= N_NODES) return;
    int lane = threadIdx.x & 63;
    int g = lane >> 3;
    int t = lane & 7;
    int beg = row_beg[n], end = row_end[n];

    f16x2 qh[4];
    {
        const float* qrow = &q[(size_t)n * HDIM + t * 8];
        float4 f0 = *(const float4*)qrow;
        float4 f1 = *(const float4*)(qrow + 4);
        qh[0][0] = (_Float16)f0.x; qh[0][1] = (_Float16)f0.y;
        qh[1][0] = (_Float16)f0.z; qh[1][1] = (_Float16)f0.w;
        qh[2][0] = (_Float16)f1.x; qh[2][1] = (_Float16)f1.y;
        qh[3][0] = (_Float16)f1.z; qh[3][1] = (_Float16)f1.w;
    }

    f16x2 z = {(_Float16)0.f, (_Float16)0.f};
    float mA = -1e30f, sA = 0.f, mB = -1e30f, sB = 0.f;
    f16x2 a0A = z, a1A = z, a2A = z, a3A = z;
    f16x2 a0B = z, a1B = z, a2B = z, a3B = z;

    for (int i = beg; i < end; i += 16) {
        int eA = i + g;
        int eB = i + 8 + g;
        bool vA = (eA < end);
        bool vB = (eB < end);
        int srcA = csr_src[vA ? eA : beg];
        int srcB = csr_src[vB ? eB : beg];
        uint4 kuA = *(const uint4*)&k16[(size_t)srcA * HDIM + t * 8];
        uint4 vuA = *(const uint4*)&v16[(size_t)srcA * HDIM + t * 8];
        uint4 kuB = *(const uint4*)&k16[(size_t)srcB * HDIM + t * 8];
        uint4 vuB = *(const uint4*)&v16[(size_t)srcB * HDIM + t * 8];

        float pA, pB;
#if __has_builtin(__builtin_amdgcn_fdot2)
        pA = __builtin_amdgcn_fdot2(qh[0], as_h2(kuA.x), 0.f, false);
        pB = __builtin_amdgcn_fdot2(qh[0], as_h2(kuB.x), 0.f, false);
        pA = __builtin_amdgcn_fdot2(qh[1], as_h2(kuA.y), pA, false);
        pB = __builtin_amdgcn_fdot2(qh[1], as_h2(kuB.y), pB, false);
        pA = __builtin_amdgcn_fdot2(qh[2], as_h2(kuA.z), pA, false);
        pB = __builtin_amdgcn_fdot2(qh[2], as_h2(kuB.z), pB, false);
        pA = __builtin_amdgcn_fdot2(qh[3], as_h2(kuA.w), pA, false);
        pB = __builtin_amdgcn_fdot2(qh[3], as_h2(kuB.w), pB, false);
#else
        {
            f16x2 k0 = as_h2(kuA.x), k1 = as_h2(kuA.y), k2 = as_h2(kuA.z), k3 = as_h2(kuA.w);
            pA = (float)qh[0][0]*(float)k0[0] + (float)qh[0][1]*(float)k0[1]
               + (float)qh[1][0]*(float)k1[0] + (float)qh[1][1]*(float)k1[1]
               + (float)qh[2][0]*(float)k2[0] + (float)qh[2][1]*(float)k2[1]
               + (float)qh[3][0]*(float)k3[0] + (float)qh[3][1]*(float)k3[1];
            k0 = as_h2(kuB.x); k1 = as_h2(kuB.y); k2 = as_h2(kuB.z); k3 = as_h2(kuB.w);
            pB = (float)qh[0][0]*(float)k0[0] + (float)qh[0][1]*(float)k0[1]
               + (float)qh[1][0]*(float)k1[0] + (float)qh[1][1]*(float)k1[1]
               + (float)qh[2][0]*(float)k2[0] + (float)qh[2][1]*(float)k2[1]
               + (float)qh[3][0]*(float)k3[0] + (float)qh[3][1]*(float)k3[1];
        }
#endif
        pA += __shfl_xor(pA, 1, 64);
        pB += __shfl_xor(pB, 1, 64);
        pA += __shfl_xor(pA, 2, 64);
        pB += __shfl_xor(pB, 2, 64);
        pA += __shfl_xor(pA, 4, 64);
        pB += __shfl_xor(pB, 4, 64);

        float aA = vA ? pA * 0.125f : -INFINITY;
        float aB = vB ? pB * 0.125f : -INFINITY;

        float mnA = fmaxf(mA, aA);
        float scA = __expf(mA - mnA);
        float ewA = __expf(aA - mnA);
        sA = sA * scA + ewA;
        mA = mnA;
        float mnB = fmaxf(mB, aB);
        float scB = __expf(mB - mnB);
        float ewB = __expf(aB - mnB);
        sB = sB * scB + ewB;
        mB = mnB;

        _Float16 scAh = (_Float16)scA, ewAh = (_Float16)ewA;
        _Float16 scBh = (_Float16)scB, ewBh = (_Float16)ewB;
        f16x2 scA2 = {scAh, scAh}, ewA2 = {ewAh, ewAh};
        f16x2 scB2 = {scBh, scBh}, ewB2 = {ewBh, ewBh};
        a0A = a0A * scA2 + as_h2(vuA.x) * ewA2;
        a0B = a0B * scB2 + as_h2(vuB.x) * ewB2;
        a1A = a1A * scA2 + as_h2(vuA.y) * ewA2;
        a1B = a1B * scB2 + as_h2(vuB.y) * ewB2;
        a2A = a2A * scA2 + as_h2(vuA.z) * ewA2;
        a2B = a2B * scB2 + as_h2(vuB.z) * ewB2;
        a3A = a3A * scA2 + as_h2(vuA.w) * ewA2;
        a3B = a3B * scB2 + as_h2(vuB.w) * ewB2;
    }

    // merge state B into A (lane-local)
    {
        float mn = fmaxf(mA, mB);
        float c1 = __expf(mA - mn);
        float c2 = __expf(mB - mn);
        sA = sA * c1 + sB * c2;
        mA = mn;
        _Float16 c1h = (_Float16)c1, c2h = (_Float16)c2;
        f16x2 c12 = {c1h, c1h}, c22 = {c2h, c2h};
        a0A = a0A * c12 + a0B * c22;
        a1A = a1A * c12 + a1B * c22;
        a2A = a2A * c12 + a2B * c22;
        a3A = a3A * c12 + a3B * c22;
    }

    // merge the 8 group-local softmax states (offsets 8,16,32)
    #pragma unroll
    for (int off = 8; off <= 32; off <<= 1) {
        float m2 = __shfl_xor(mA, off, 64);
        float s2 = __shfl_xor(sA, off, 64);
        int w0 = __shfl_xor((int)h2_as_u(a0A), off, 64);
        int w1 = __shfl_xor((int)h2_as_u(a1A), off, 64);
        int w2 = __shfl_xor((int)h2_as_u(a2A), off, 64);
        int w3 = __shfl_xor((int)h2_as_u(a3A), off, 64);
        float mn = fmaxf(mA, m2);
        float c1 = __expf(mA - mn);
        float c2 = __expf(m2 - mn);
        sA = sA * c1 + s2 * c2;
        mA = mn;
        _Float16 c1h = (_Float16)c1, c2h = (_Float16)c2;
        f16x2 c12 = {c1h, c1h}, c22 = {c2h, c2h};
        a0A = a0A * c12 + as_h2((unsigned)w0) * c22;
        a1A = a1A * c12 + as_h2((unsigned)w1) * c22;
        a2A = a2A * c12 + as_h2((unsigned)w2) * c22;
        a3A = a3A * c12 + as_h2((unsigned)w3) * c22;
    }

    if (g == 0) {
        float inv = (sA > 0.f) ? (1.f / sA) : 0.f;
        const float* skrow = &skip[(size_t)n * HDIM + t * 8];
        float4 s0 = *(const float4*)skrow;
        float4 s1 = *(const float4*)(skrow + 4);
        float4 o0, o1;
        o0.x = (float)a0A[0] * inv + s0.x;
        o0.y = (float)a0A[1] * inv + s0.y;
        o0.z = (float)a1A[0] * inv + s0.z;
        o0.w = (float)a1A[1] * inv + s0.w;
        o1.x = (float)a2A[0] * inv + s1.x;
        o1.y = (float)a2A[1] * inv + s1.y;
        o1.z = (float)a3A[0] * inv + s1.z;
        o1.w = (float)a3A[1] * inv + s1.w;
        if (do_relu) {
            o0.x = fmaxf(o0.x, 0.f); o0.y = fmaxf(o0.y, 0.f);
            o0.z = fmaxf(o0.z, 0.f); o0.w = fmaxf(o0.w, 0.f);
            o1.x = fmaxf(o1.x, 0.f); o1.y = fmaxf(o1.y, 0.f);
            o1.z = fmaxf(o1.z, 0.f); o1.w = fmaxf(o1.w, 0.f);
        }
        float* orow = &hout[(size_t)n * HDIM + t * 8];
        *(float4*)orow = o0;
        *(float4*)(orow + 4) = o1;
    }
}

// ---------- mean pool: run-length accumulate (batch sorted), 64 nodes/wave ----------
__global__ __launch_bounds__(256) void pool_kernel(
    const float* __restrict__ h, const int* __restrict__ batch,
    float* __restrict__ sums, float* __restrict__ cnt)
{
    int wid = blockIdx.x * 4 + (threadIdx.x >> 6);
    int n0 = wid * 64;
    if (n0 >= N_NODES) return;
    int lane = threadIdx.x & 63;
    int nend = min(n0 + 64, N_NODES);
    float acc = 0.f;
    int b_cur = batch[n0];
    int run = 0;
    for (int n = n0; n < nend; n++) {
        int b = batch[n];
        if (b != b_cur) {
            atomicAdd(&sums[b_cur * HDIM + lane], acc);
            if (lane == 0) atomicAdd(&cnt[b_cur], (float)run);
            acc = 0.f; run = 0; b_cur = b;
        }
        acc += h[(size_t)n * HDIM + lane];
        run++;
    }
    atomicAdd(&sums[b_cur * HDIM + lane], acc);
    if (lane == 0) atomicAdd(&cnt[b_cur], (float)run);
}

// ---------- head ----------
__global__ void head_kernel(
    const float* __restrict__ sums, const float* __restrict__ cnt,
    const float* __restrict__ Wl, const float* __restrict__ bl,
    float* __restrict__ out)
{
    int tid = threadIdx.x;
    if (tid >= NB * NC) return;
    int b = tid / NC, c = tid % NC;
    float cc = fmaxf(cnt[b], 1.0f);
    float acc = bl[c];
    #pragma unroll
    for (int f = 0; f < HDIM; f++)
        acc += (sums[b * HDIM + f] / cc) * Wl[c * HDIM + f];
    out[tid] = acc;
}

extern "C" void kernel_launch(void* const* d_in, const int* in_sizes, int n_in,
                              void* d_out, int out_size, void* d_ws, size_t ws_size,
                              hipStream_t stream)
{
    const float* x     = (const float*)d_in[0];
    const int*   ei    = (const int*)d_in[1];
    const int*   batch = (const int*)d_in[2];

    const float* W[3][4];
    const float* B[3][4];
    for (int l = 0; l < 3; l++)
        for (int j = 0; j < 4; j++) {
            W[l][j] = (const float*)d_in[3 + l * 8 + j * 2];
            B[l][j] = (const float*)d_in[3 + l * 8 + j * 2 + 1];
        }
    const float* Wl = (const float*)d_in[27];
    const float* bl = (const float*)d_in[28];
    float* out = (float*)d_out;

    const size_t NF = (size_t)N_NODES * HDIM;
    char* w = (char*)d_ws;
    float*          h       = (float*)w;          w += NF * 4;
    float*          q       = (float*)w;          w += NF * 4;
    unsigned short* k16     = (unsigned short*)w; w += NF * 2;
    unsigned short* v16     = (unsigned short*)w; w += NF * 2;
    float*          skip    = (float*)w;          w += NF * 4;
    int*            csr_src = (int*)w;            w += (size_t)NBUCK * BCAP * 4;
    int*            bedge   = (int*)w;            w += (size_t)NBUCK * BCAP * 4;
    int*            row_bg  = (int*)w;            w += (size_t)N_NODES * 4;
    int*            row_en  = (int*)w;            w += (size_t)N_NODES * 4;
    int*            gcursor = (int*)w;            w += (size_t)NBUCK * 4;
    float*          sums    = (float*)w;          w += (size_t)NB * HDIM * 4;
    float*          cnt     = (float*)w;          w += (size_t)NB * 4;
    unsigned short* whi[3];
    unsigned short* wlo[3];
    const int wsz[3] = {64 * F_IN, 64 * HDIM, 64 * HDIM};   // per-mat elems
    for (int l = 0; l < 3; l++) {
        whi[l] = (unsigned short*)w; w += (size_t)4 * wsz[l] * 2;
        wlo[l] = (unsigned short*)w; w += (size_t)4 * wsz[l] * 2;
    }

    const int gemm_gx = (N_NODES + 63) / 64;
    const int node_gx = (N_NODES + 3) / 4;
    const int pool_gx = (N_NODES + 64 * 4 - 1) / (64 * 4);

    // ----- W split to bf16 hi/lo (once) -----
    for (int l = 0; l < 3; l++) {
        int n = wsz[l];
        wsplit<<<(4 * n + 255) / 256, 256, 0, stream>>>(
            W[l][0], W[l][1], W[l][2], W[l][3], whi[l], wlo[l], n);
    }

    // ----- CSR build via padded-bucket counting sort (once) -----
    init_cursor<<<1, 256, 0, stream>>>(gcursor);
    bucket_scatter<<<EW_GRID, 256, 0, stream>>>(ei, gcursor, bedge);
    csr_from_buckets<<<NBUCK, 256, 0, stream>>>(bedge, gcursor, row_bg, row_en, csr_src);

    for (int l = 0; l < 3; l++) {
        if (l == 0) {
            qkvs_gemm_mfma<F_IN><<<gemm_gx, 256, 0, stream>>>(
                x, whi[0], wlo[0], B[0][0], B[0][1], B[0][2], B[0][3],
                q, k16, v16, skip);
        } else {
            qkvs_gemm_mfma<HDIM><<<gemm_gx, 256, 0, stream>>>(
                h, whi[l], wlo[l], B[l][0], B[l][1], B[l][2], B[l][3],
                q, k16, v16, skip);
        }
        attn_fused<<<node_gx, 256, 0, stream>>>(
            row_bg, row_en, csr_src, q, k16, v16, skip, h, l < 2 ? 1 : 0);
    }

    hipMemsetAsync(sums, 0, (size_t)NB * HDIM * 4, stream);
    hipMemsetAsync(cnt,  0, (size_t)NB * 4, stream);
    pool_kernel<<<pool_gx, 256, 0, stream>>>(h, batch, sums, cnt);
    head_kernel<<<1, 640, 0, stream>>>(sums, cnt, Wl, bl, out);
}

// Round 21
// 410.150 us; speedup vs baseline: 1.3011x; 1.0042x over previous
//
#include <hip/hip_runtime.h>
#include <math.h>

#define N_NODES 100000
#define N_EDGES 1600000
#define NB 64
#define F_IN 128
#define HDIM 64
#define NC 10

#define BSHIFT 9
#define BUCKET_NODES (1 << BSHIFT)                          // 512
#define NBUCK ((N_NODES + BUCKET_NODES - 1) >> BSHIFT)      // 196
#define BCAP 16384                                          // padded bucket capacity
#define EW_CHUNK 4096
#define EW_GRID ((N_EDGES + EW_CHUNK - 1) / EW_CHUNK)       // 391

typedef __attribute__((ext_vector_type(8))) short bf16x8;
typedef __attribute__((ext_vector_type(4))) float f32x4;
typedef _Float16 f16x2 __attribute__((ext_vector_type(2)));

// ---------- bf16 helpers (GEMM compute path) ----------
__device__ __forceinline__ unsigned short f2bf(float f) {
    unsigned u = __float_as_uint(f);
    u += 0x7FFFu + ((u >> 16) & 1u);    // round to nearest even
    return (unsigned short)(u >> 16);
}
__device__ __forceinline__ float bf2f(unsigned short b) {
    return __uint_as_float((unsigned)b << 16);
}

// ---------- fp16 helpers (k/v storage) ----------
__device__ __forceinline__ unsigned pack2h(float a, float b) {
    union { f16x2 h; unsigned u; } c;
    c.h[0] = (_Float16)a;
    c.h[1] = (_Float16)b;
    return c.u;
}
__device__ __forceinline__ f16x2 as_h2(unsigned u) {
    union { unsigned u; f16x2 h; } c;
    c.u = u;
    return c.h;
}

// ---------- W split: W -> bf16 hi + bf16 lo (residual) ----------
__global__ __launch_bounds__(256) void wsplit(
    const float* __restrict__ W0, const float* __restrict__ W1,
    const float* __restrict__ W2, const float* __restrict__ W3,
    unsigned short* __restrict__ hi, unsigned short* __restrict__ lo, int n)
{
    int i = blockIdx.x * 256 + threadIdx.x;
    if (i >= 4 * n) return;
    const float* Ws[4] = {W0, W1, W2, W3};
    float w = Ws[i / n][i % n];
    unsigned short h = f2bf(w);
    hi[i] = h;
    lo[i] = f2bf(w - bf2f(h));
}

// ---------- fused q/k/v/skip GEMM via MFMA, OPERAND-SWAPPED (r18 win) ----------
template<int K>
__global__ __launch_bounds__(256) void qkvs_gemm_mfma(
    const float* __restrict__ xin,
    const unsigned short* __restrict__ whi,
    const unsigned short* __restrict__ wlo,
    const float* __restrict__ bq, const float* __restrict__ bk,
    const float* __restrict__ bv, const float* __restrict__ bs,
    float* __restrict__ q, unsigned short* __restrict__ k16,
    unsigned short* __restrict__ v16, float* __restrict__ sk)
{
    constexpr int NCH = K / 32;
    constexpr int NFB = 4 * NCH * 2;        // per-mat: feat-tiles * chunks * (hi,lo)
    __shared__ short Wlds[NFB * 512];       // 1 KB per fragment-block

    const int tid = threadIdx.x;
    const int wv  = tid >> 6;
    const int l   = tid & 63;
    const int lr  = l & 15;      // B-col (node) / A-row (feat) / D-col (node)
    const int lg  = l >> 4;      // k-group (8 consecutive k); D-row group
    const int n0  = blockIdx.x * 64 + wv * 16;
    const int node = n0 + lr;
    const bool nok = node < N_NODES;

    bf16x8 Xhi[NCH], Xlo[NCH];
    {
        const float* xr = xin + (size_t)(nok ? node : 0) * K + lg * 8;
        #pragma unroll
        for (int c = 0; c < NCH; c++) {
            float4 f0, f1;
            if (nok) {
                f0 = *(const float4*)(xr + c * 32);
                f1 = *(const float4*)(xr + c * 32 + 4);
            } else {
                f0 = make_float4(0.f, 0.f, 0.f, 0.f);
                f1 = f0;
            }
            float xv[8] = {f0.x, f0.y, f0.z, f0.w, f1.x, f1.y, f1.z, f1.w};
            #pragma unroll
            for (int j = 0; j < 8; j++) {
                unsigned short hb = f2bf(xv[j]);
                Xhi[c][j] = (short)hb;
                Xlo[c][j] = (short)f2bf(xv[j] - bf2f(hb));
            }
        }
    }

    const float* Bm[4] = {bq, bk, bv, bs};

    for (int mat = 0; mat < 4; mat++) {
        if (mat) __syncthreads();
        #pragma unroll
        for (int it = 0; it < NFB / 4; it++) {
            int fb   = it * 4 + wv;
            int hsel = fb & 1;
            int rest = fb >> 1;             // ft*NCH + c
            int c    = rest & (NCH - 1);
            int ft   = rest / NCH;
            const unsigned short* src = hsel ? wlo : whi;
            size_t goff = (size_t)(mat * 64 + ft * 16 + lr) * K + c * 32 + lg * 8;
            uint4 d = *(const uint4*)&src[goff];
            *(uint4*)&Wlds[fb * 512 + l * 8] = d;
        }
        __syncthreads();

        #pragma unroll
        for (int ft = 0; ft < 4; ft++) {
            f32x4 acc = {0.f, 0.f, 0.f, 0.f};
            #pragma unroll
            for (int c = 0; c < NCH; c++) {
                const int fb = (ft * NCH + c) << 1;
                bf16x8 Whi = *(const bf16x8*)&Wlds[fb * 512 + l * 8];
                bf16x8 Wlo = *(const bf16x8*)&Wlds[(fb + 1) * 512 + l * 8];
                acc = __builtin_amdgcn_mfma_f32_16x16x32_bf16(Whi, Xhi[c], acc, 0, 0, 0);
                acc = __builtin_amdgcn_mfma_f32_16x16x32_bf16(Wlo, Xhi[c], acc, 0, 0, 0);
                acc = __builtin_amdgcn_mfma_f32_16x16x32_bf16(Whi, Xlo[c], acc, 0, 0, 0);
            }
            if (nok) {
                float4 b4 = *(const float4*)&Bm[mat][ft * 16 + lg * 4];
                float v0 = acc[0] + b4.x;
                float v1 = acc[1] + b4.y;
                float v2 = acc[2] + b4.z;
                float v3 = acc[3] + b4.w;
                size_t off = (size_t)node * HDIM + ft * 16 + lg * 4;
                if (mat == 0) {
                    *(float4*)&q[off] = make_float4(v0, v1, v2, v3);
                } else if (mat == 3) {
                    *(float4*)&sk[off] = make_float4(v0, v1, v2, v3);
                } else {
                    uint2 p;
                    p.x = pack2h(v0, v1);
                    p.y = pack2h(v2, v3);
                    if (mat == 1) *(uint2*)&k16[off] = p;
                    else          *(uint2*)&v16[off] = p;
                }
            }
        }
    }
}

// ---------- CSR build (padded buckets) ----------
__global__ void init_cursor(int* __restrict__ gcursor)
{
    int t = threadIdx.x;
    if (t < NBUCK) gcursor[t] = t * BCAP;
}

// packed entry: (dst_local << 17) | src
__global__ __launch_bounds__(256) void bucket_scatter(
    const int* __restrict__ ei, int* __restrict__ gcursor, int* __restrict__ bedge)
{
    __shared__ int hist[NBUCK];
    __shared__ int base[NBUCK];
    for (int i = threadIdx.x; i < NBUCK; i += 256) hist[i] = 0;
    __syncthreads();
    int e0 = blockIdx.x * EW_CHUNK;
    #pragma unroll
    for (int i = 0; i < EW_CHUNK / 256; i++) {
        int e = e0 + i * 256 + threadIdx.x;
        if (e < N_EDGES) atomicAdd(&hist[ei[N_EDGES + e] >> BSHIFT], 1);
    }
    __syncthreads();
    for (int i = threadIdx.x; i < NBUCK; i += 256)
        base[i] = hist[i] ? atomicAdd(&gcursor[i], hist[i]) : 0;
    __syncthreads();
    for (int i = threadIdx.x; i < NBUCK; i += 256) hist[i] = 0;
    __syncthreads();
    #pragma unroll
    for (int i = 0; i < EW_CHUNK / 256; i++) {
        int e = e0 + i * 256 + threadIdx.x;
        if (e < N_EDGES) {
            int src = ei[e];
            int dst = ei[N_EDGES + e];
            int b = dst >> BSHIFT;
            int pos = base[b] + atomicAdd(&hist[b], 1);
            bedge[pos] = ((dst & (BUCKET_NODES - 1)) << 17) | src;
        }
    }
}

// one WG per bucket: LDS hist -> scan -> row_beg/row_end (padded csr) -> place
__global__ __launch_bounds__(256) void csr_from_buckets(
    const int* __restrict__ bedge, const int* __restrict__ gcursor,
    int* __restrict__ row_beg, int* __restrict__ row_end,
    int* __restrict__ csr_src)
{
    __shared__ int cur[BUCKET_NODES];   // 512
    __shared__ int psum[256];
    const int b = blockIdx.x;
    const int dst0 = b << BSHIFT;
    const int t = threadIdx.x;
    const int beg = b * BCAP;
    const int cnt = gcursor[b] - beg;

    for (int i = t; i < BUCKET_NODES; i += 256) cur[i] = 0;
    __syncthreads();

    for (int i = t; i < cnt; i += 256)
        atomicAdd(&cur[bedge[beg + i] >> 17], 1);
    __syncthreads();

    int a0 = cur[2 * t], a1 = cur[2 * t + 1];
    int pair = a0 + a1;
    psum[t] = pair;
    __syncthreads();
    for (int off = 1; off < 256; off <<= 1) {
        int u = (t >= off) ? psum[t - off] : 0;
        __syncthreads();
        psum[t] += u;
        __syncthreads();
    }
    int ex = psum[t] - pair;            // exclusive prefix of this pair

    int d0 = dst0 + 2 * t, d1 = d0 + 1;
    int g0 = beg + ex, g1 = beg + ex + a0;
    if (d0 < N_NODES) { row_beg[d0] = g0; row_end[d0] = g0 + a0; }
    if (d1 < N_NODES) { row_beg[d1] = g1; row_end[d1] = g1 + a1; }
    cur[2 * t] = g0;
    cur[2 * t + 1] = g1;
    __syncthreads();

    for (int i = t; i < cnt; i += 256) {
        int ed = bedge[beg + i];
        int pos = atomicAdd(&cur[ed >> 17], 1);
        csr_src[pos] = ed & 0x1FFFF;
    }
}

// ---------- fused attention: wave per dst, 16 edges/iter, MAX-FREE softmax ----------
// softmax is shift-invariant; alpha range (~±3) makes exp() safe in fp32.
// exp(-inf)=0 handles tail slots for free. fp32 accumulators via v_fma_mix.
// lane = g*8 + t : g = edge slot (0..7), t = feature octet (features 8t..8t+7)
__global__ __launch_bounds__(256) void attn_fused(
    const int* __restrict__ row_beg, const int* __restrict__ row_end,
    const int* __restrict__ csr_src,
    const float* __restrict__ q, const unsigned short* __restrict__ k16,
    const unsigned short* __restrict__ v16, const float* __restrict__ skip,
    float* __restrict__ hout, int do_relu)
{
    int n = blockIdx.x * 4 + (threadIdx.x >> 6);
    if (n >= N_NODES) return;
    int lane = threadIdx.x & 63;
    int g = lane >> 3;
    int t = lane & 7;
    int beg = row_beg[n], end = row_end[n];

    f16x2 qh[4];
    {
        const float* qrow = &q[(size_t)n * HDIM + t * 8];
        float4 f0 = *(const float4*)qrow;
        float4 f1 = *(const float4*)(qrow + 4);
        qh[0][0] = (_Float16)f0.x; qh[0][1] = (_Float16)f0.y;
        qh[1][0] = (_Float16)f0.z; qh[1][1] = (_Float16)f0.w;
        qh[2][0] = (_Float16)f1.x; qh[2][1] = (_Float16)f1.y;
        qh[3][0] = (_Float16)f1.z; qh[3][1] = (_Float16)f1.w;
    }

    float sA = 0.f, sB = 0.f;
    float acA[8] = {0.f, 0.f, 0.f, 0.f, 0.f, 0.f, 0.f, 0.f};
    float acB[8] = {0.f, 0.f, 0.f, 0.f, 0.f, 0.f, 0.f, 0.f};

    for (int i = beg; i < end; i += 16) {
        int eA = i + g;
        int eB = i + 8 + g;
        bool vA = (eA < end);
        bool vB = (eB < end);
        int srcA = csr_src[vA ? eA : beg];
        int srcB = csr_src[vB ? eB : beg];
        uint4 kuA = *(const uint4*)&k16[(size_t)srcA * HDIM + t * 8];
        uint4 vuA = *(const uint4*)&v16[(size_t)srcA * HDIM + t * 8];
        uint4 kuB = *(const uint4*)&k16[(size_t)srcB * HDIM + t * 8];
        uint4 vuB = *(const uint4*)&v16[(size_t)srcB * HDIM + t * 8];

        float pA, pB;
#if __has_builtin(__builtin_amdgcn_fdot2)
        pA = __builtin_amdgcn_fdot2(qh[0], as_h2(kuA.x), 0.f, false);
        pB = __builtin_amdgcn_fdot2(qh[0], as_h2(kuB.x), 0.f, false);
        pA = __builtin_amdgcn_fdot2(qh[1], as_h2(kuA.y), pA, false);
        pB = __builtin_amdgcn_fdot2(qh[1], as_h2(kuB.y), pB, false);
        pA = __builtin_amdgcn_fdot2(qh[2], as_h2(kuA.z), pA, false);
        pB = __builtin_amdgcn_fdot2(qh[2], as_h2(kuB.z), pB, false);
        pA = __builtin_amdgcn_fdot2(qh[3], as_h2(kuA.w), pA, false);
        pB = __builtin_amdgcn_fdot2(qh[3], as_h2(kuB.w), pB, false);
#else
        {
            f16x2 k0 = as_h2(kuA.x), k1 = as_h2(kuA.y), k2 = as_h2(kuA.z), k3 = as_h2(kuA.w);
            pA = (float)qh[0][0]*(float)k0[0] + (float)qh[0][1]*(float)k0[1]
               + (float)qh[1][0]*(float)k1[0] + (float)qh[1][1]*(float)k1[1]
               + (float)qh[2][0]*(float)k2[0] + (float)qh[2][1]*(float)k2[1]
               + (float)qh[3][0]*(float)k3[0] + (float)qh[3][1]*(float)k3[1];
            k0 = as_h2(kuB.x); k1 = as_h2(kuB.y); k2 = as_h2(kuB.z); k3 = as_h2(kuB.w);
            pB = (float)qh[0][0]*(float)k0[0] + (float)qh[0][1]*(float)k0[1]
               + (float)qh[1][0]*(float)k1[0] + (float)qh[1][1]*(float)k1[1]
               + (float)qh[2][0]*(float)k2[0] + (float)qh[2][1]*(float)k2[1]
               + (float)qh[3][0]*(float)k3[0] + (float)qh[3][1]*(float)k3[1];
        }
#endif
        pA += __shfl_xor(pA, 1, 64);
        pB += __shfl_xor(pB, 1, 64);
        pA += __shfl_xor(pA, 2, 64);
        pB += __shfl_xor(pB, 2, 64);
        pA += __shfl_xor(pA, 4, 64);
        pB += __shfl_xor(pB, 4, 64);

        float ewA = __expf(vA ? pA * 0.125f : -INFINITY);   // 0 for invalid
        float ewB = __expf(vB ? pB * 0.125f : -INFINITY);
        sA += ewA;
        sB += ewB;

        f16x2 a0 = as_h2(vuA.x), a1 = as_h2(vuA.y), a2 = as_h2(vuA.z), a3 = as_h2(vuA.w);
        f16x2 b0 = as_h2(vuB.x), b1 = as_h2(vuB.y), b2 = as_h2(vuB.z), b3 = as_h2(vuB.w);
        acA[0] += (float)a0[0] * ewA;  acB[0] += (float)b0[0] * ewB;
        acA[1] += (float)a0[1] * ewA;  acB[1] += (float)b0[1] * ewB;
        acA[2] += (float)a1[0] * ewA;  acB[2] += (float)b1[0] * ewB;
        acA[3] += (float)a1[1] * ewA;  acB[3] += (float)b1[1] * ewB;
        acA[4] += (float)a2[0] * ewA;  acB[4] += (float)b2[0] * ewB;
        acA[5] += (float)a2[1] * ewA;  acB[5] += (float)b2[1] * ewB;
        acA[6] += (float)a3[0] * ewA;  acB[6] += (float)b3[0] * ewB;
        acA[7] += (float)a3[1] * ewA;  acB[7] += (float)b3[1] * ewB;
    }

    // lane-local merge of state B into A (pure adds)
    sA += sB;
    #pragma unroll
    for (int j = 0; j < 8; j++) acA[j] += acB[j];

    // cross-lane merge (offsets 8,16,32) — pure adds
    #pragma unroll
    for (int off = 8; off <= 32; off <<= 1) {
        sA += __shfl_xor(sA, off, 64);
        #pragma unroll
        for (int j = 0; j < 8; j++) acA[j] += __shfl_xor(acA[j], off, 64);
    }

    if (g == 0) {
        float inv = (sA > 0.f) ? (1.f / sA) : 0.f;
        const float* skrow = &skip[(size_t)n * HDIM + t * 8];
        float4 s0 = *(const float4*)skrow;
        float4 s1 = *(const float4*)(skrow + 4);
        float4 o0, o1;
        o0.x = acA[0] * inv + s0.x;
        o0.y = acA[1] * inv + s0.y;
        o0.z = acA[2] * inv + s0.z;
        o0.w = acA[3] * inv + s0.w;
        o1.x = acA[4] * inv + s1.x;
        o1.y = acA[5] * inv + s1.y;
        o1.z = acA[6] * inv + s1.z;
        o1.w = acA[7] * inv + s1.w;
        if (do_relu) {
            o0.x = fmaxf(o0.x, 0.f); o0.y = fmaxf(o0.y, 0.f);
            o0.z = fmaxf(o0.z, 0.f); o0.w = fmaxf(o0.w, 0.f);
            o1.x = fmaxf(o1.x, 0.f); o1.y = fmaxf(o1.y, 0.f);
            o1.z = fmaxf(o1.z, 0.f); o1.w = fmaxf(o1.w, 0.f);
        }
        float* orow = &hout[(size_t)n * HDIM + t * 8];
        *(float4*)orow = o0;
        *(float4*)(orow + 4) = o1;
    }
}

// ---------- mean pool: run-length accumulate (batch sorted), 64 nodes/wave ----------
__global__ __launch_bounds__(256) void pool_kernel(
    const float* __restrict__ h, const int* __restrict__ batch,
    float* __restrict__ sums, float* __restrict__ cnt)
{
    int wid = blockIdx.x * 4 + (threadIdx.x >> 6);
    int n0 = wid * 64;
    if (n0 >= N_NODES) return;
    int lane = threadIdx.x & 63;
    int nend = min(n0 + 64, N_NODES);
    float acc = 0.f;
    int b_cur = batch[n0];
    int run = 0;
    for (int n = n0; n < nend; n++) {
        int b = batch[n];
        if (b != b_cur) {
            atomicAdd(&sums[b_cur * HDIM + lane], acc);
            if (lane == 0) atomicAdd(&cnt[b_cur], (float)run);
            acc = 0.f; run = 0; b_cur = b;
        }
        acc += h[(size_t)n * HDIM + lane];
        run++;
    }
    atomicAdd(&sums[b_cur * HDIM + lane], acc);
    if (lane == 0) atomicAdd(&cnt[b_cur], (float)run);
}

// ---------- head ----------
__global__ void head_kernel(
    const float* __restrict__ sums, const float* __restrict__ cnt,
    const float* __restrict__ Wl, const float* __restrict__ bl,
    float* __restrict__ out)
{
    int tid = threadIdx.x;
    if (tid >= NB * NC) return;
    int b = tid / NC, c = tid % NC;
    float cc = fmaxf(cnt[b], 1.0f);
    float acc = bl[c];
    #pragma unroll
    for (int f = 0; f < HDIM; f++)
        acc += (sums[b * HDIM + f] / cc) * Wl[c * HDIM + f];
    out[tid] = acc;
}

extern "C" void kernel_launch(void* const* d_in, const int* in_sizes, int n_in,
                              void* d_out, int out_size, void* d_ws, size_t ws_size,
                              hipStream_t stream)
{
    const float* x     = (const float*)d_in[0];
    const int*   ei    = (const int*)d_in[1];
    const int*   batch = (const int*)d_in[2];

    const float* W[3][4];
    const float* B[3][4];
    for (int l = 0; l < 3; l++)
        for (int j = 0; j < 4; j++) {
            W[l][j] = (const float*)d_in[3 + l * 8 + j * 2];
            B[l][j] = (const float*)d_in[3 + l * 8 + j * 2 + 1];
        }
    const float* Wl = (const float*)d_in[27];
    const float* bl = (const float*)d_in[28];
    float* out = (float*)d_out;

    const size_t NF = (size_t)N_NODES * HDIM;
    char* w = (char*)d_ws;
    float*          h       = (float*)w;          w += NF * 4;
    float*          q       = (float*)w;          w += NF * 4;
    unsigned short* k16     = (unsigned short*)w; w += NF * 2;
    unsigned short* v16     = (unsigned short*)w; w += NF * 2;
    float*          skip    = (float*)w;          w += NF * 4;
    int*            csr_src = (int*)w;            w += (size_t)NBUCK * BCAP * 4;
    int*            bedge   = (int*)w;            w += (size_t)NBUCK * BCAP * 4;
    int*            row_bg  = (int*)w;            w += (size_t)N_NODES * 4;
    int*            row_en  = (int*)w;            w += (size_t)N_NODES * 4;
    int*            gcursor = (int*)w;            w += (size_t)NBUCK * 4;
    float*          sums    = (float*)w;          w += (size_t)NB * HDIM * 4;
    float*          cnt     = (float*)w;          w += (size_t)NB * 4;
    unsigned short* whi[3];
    unsigned short* wlo[3];
    const int wsz[3] = {64 * F_IN, 64 * HDIM, 64 * HDIM};   // per-mat elems
    for (int l = 0; l < 3; l++) {
        whi[l] = (unsigned short*)w; w += (size_t)4 * wsz[l] * 2;
        wlo[l] = (unsigned short*)w; w += (size_t)4 * wsz[l] * 2;
    }

    const int gemm_gx = (N_NODES + 63) / 64;
    const int node_gx = (N_NODES + 3) / 4;
    const int pool_gx = (N_NODES + 64 * 4 - 1) / (64 * 4);

    // ----- W split to bf16 hi/lo (once) -----
    for (int l = 0; l < 3; l++) {
        int n = wsz[l];
        wsplit<<<(4 * n + 255) / 256, 256, 0, stream>>>(
            W[l][0], W[l][1], W[l][2], W[l][3], whi[l], wlo[l], n);
    }

    // ----- CSR build via padded-bucket counting sort (once) -----
    init_cursor<<<1, 256, 0, stream>>>(gcursor);
    bucket_scatter<<<EW_GRID, 256, 0, stream>>>(ei, gcursor, bedge);
    csr_from_buckets<<<NBUCK, 256, 0, stream>>>(bedge, gcursor, row_bg, row_en, csr_src);

    for (int l = 0; l < 3; l++) {
        if (l == 0) {
            qkvs_gemm_mfma<F_IN><<<gemm_gx, 256, 0, stream>>>(
                x, whi[0], wlo[0], B[0][0], B[0][1], B[0][2], B[0][3],
                q, k16, v16, skip);
        } else {
            qkvs_gemm_mfma<HDIM><<<gemm_gx, 256, 0, stream>>>(
                h, whi[l], wlo[l], B[l][0], B[l][1], B[l][2], B[l][3],
                q, k16, v16, skip);
        }
        attn_fused<<<node_gx, 256, 0, stream>>>(
            row_bg, row_en, csr_src, q, k16, v16, skip, h, l < 2 ? 1 : 0);
    }

    hipMemsetAsync(sums, 0, (size_t)NB * HDIM * 4, stream);
    hipMemsetAsync(cnt,  0, (size_t)NB * 4, stream);
    pool_kernel<<<pool_gx, 256, 0, stream>>>(h, batch, sums, cnt);
    head_kernel<<<1, 640, 0, stream>>>(sums, cnt, Wl, bl, out);
}

// Round 23
// 388.438 us; speedup vs baseline: 1.3739x; 1.0559x over previous
//
#include <hip/hip_runtime.h>
#include <math.h>

#define N_NODES 100000
#define N_EDGES 1600000
#define NB 64
#define F_IN 128
#define HDIM 64
#define NC 10

#define BSHIFT 9
#define BUCKET_NODES (1 << BSHIFT)                          // 512
#define NBUCK ((N_NODES + BUCKET_NODES - 1) >> BSHIFT)      // 196
#define BCAP 16384                                          // padded bucket capacity
#define EW_CHUNK 4096
#define EW_GRID ((N_EDGES + EW_CHUNK - 1) / EW_CHUNK)       // 391

typedef __attribute__((ext_vector_type(8))) short bf16x8;
typedef __attribute__((ext_vector_type(4))) float f32x4;
typedef __attribute__((ext_vector_type(2))) float f32x2;

// ---------- bf16 helpers (GEMM compute path) ----------
__device__ __forceinline__ unsigned short f2bf(float f) {
    unsigned u = __float_as_uint(f);
    u += 0x7FFFu + ((u >> 16) & 1u);    // round to nearest even
    return (unsigned short)(u >> 16);
}
__device__ __forceinline__ float bf2f(unsigned short b) {
    return __uint_as_float((unsigned)b << 16);
}

// ---------- fp8 helpers (k/v storage). HW cvt on gfx950; the builtin's
// `hi`/`old_hi` operands must be IMMEDIATE constants -> dedicated lo/hi fns.
#if __has_builtin(__builtin_amdgcn_cvt_pk_fp8_f32) && __has_builtin(__builtin_amdgcn_cvt_pk_f32_fp8)
__device__ __forceinline__ unsigned pack4fp8(float a, float b, float c, float d) {
    int r = 0;
    r = __builtin_amdgcn_cvt_pk_fp8_f32(a, b, r, false);   // low half
    r = __builtin_amdgcn_cvt_pk_fp8_f32(c, d, r, true);    // high half
    return (unsigned)r;
}
__device__ __forceinline__ f32x2 unpk_lo(unsigned u) {
    return __builtin_amdgcn_cvt_pk_f32_fp8((int)u, false);
}
__device__ __forceinline__ f32x2 unpk_hi(unsigned u) {
    return __builtin_amdgcn_cvt_pk_f32_fp8((int)u, true);
}
#else
__device__ __forceinline__ unsigned char f2e4m3(float f) {
    float a = fabsf(f);
    unsigned s = (__float_as_uint(f) >> 31) << 7;
    if (a > 448.f) a = 448.f;
    if (a < 0.015625f) {                 // < 2^-6: denormal, quantum 2^-9
        int qd = (int)(a * 512.f + 0.5f);
        if (qd > 7) qd = 7;
        return (unsigned char)(s | qd);
    }
    int e; float mf = frexpf(a, &e);     // a = mf * 2^e, mf in [0.5,1)
    int ee = e - 1 + 7;                  // biased exp for 1.m * 2^(e-1)
    int m = (int)((mf * 2.f - 1.f) * 8.f + 0.5f);
    if (m > 7) { m = 0; ee++; }
    if (ee > 15) { ee = 15; m = 6; }     // clamp below NaN (15,7)
    return (unsigned char)(s | (ee << 3) | m);
}
__device__ __forceinline__ float e4m3_2f(unsigned char b) {
    unsigned s = b >> 7, e = (b >> 3) & 15, m = b & 7;
    float v = e ? ldexpf(1.f + m * 0.125f, (int)e - 7) : ldexpf((float)m, -9);
    return s ? -v : v;
}
__device__ __forceinline__ unsigned pack4fp8(float a, float b, float c, float d) {
    return (unsigned)f2e4m3(a) | ((unsigned)f2e4m3(b) << 8)
         | ((unsigned)f2e4m3(c) << 16) | ((unsigned)f2e4m3(d) << 24);
}
__device__ __forceinline__ f32x2 unpk_lo(unsigned u) {
    f32x2 r;
    r[0] = e4m3_2f((unsigned char)(u & 0xFF));
    r[1] = e4m3_2f((unsigned char)((u >> 8) & 0xFF));
    return r;
}
__device__ __forceinline__ f32x2 unpk_hi(unsigned u) {
    f32x2 r;
    r[0] = e4m3_2f((unsigned char)((u >> 16) & 0xFF));
    r[1] = e4m3_2f((unsigned char)((u >> 24) & 0xFF));
    return r;
}
#endif

// ---------- W split: W -> bf16 hi + bf16 lo (residual) ----------
__global__ __launch_bounds__(256) void wsplit(
    const float* __restrict__ W0, const float* __restrict__ W1,
    const float* __restrict__ W2, const float* __restrict__ W3,
    unsigned short* __restrict__ hi, unsigned short* __restrict__ lo, int n)
{
    int i = blockIdx.x * 256 + threadIdx.x;
    if (i >= 4 * n) return;
    const float* Ws[4] = {W0, W1, W2, W3};
    float w = Ws[i / n][i % n];
    unsigned short h = f2bf(w);
    hi[i] = h;
    lo[i] = f2bf(w - bf2f(h));
}

// ---------- fused q/k/v/skip GEMM via MFMA, OPERAND-SWAPPED (r18 win) ----------
// k/v emitted as fp8 e4m3 (64 B rows -> halves attn's compulsory gather set).
template<int K>
__global__ __launch_bounds__(256) void qkvs_gemm_mfma(
    const float* __restrict__ xin,
    const unsigned short* __restrict__ whi,
    const unsigned short* __restrict__ wlo,
    const float* __restrict__ bq, const float* __restrict__ bk,
    const float* __restrict__ bv, const float* __restrict__ bs,
    float* __restrict__ q, unsigned char* __restrict__ k8,
    unsigned char* __restrict__ v8, float* __restrict__ sk)
{
    constexpr int NCH = K / 32;
    constexpr int NFB = 4 * NCH * 2;        // per-mat: feat-tiles * chunks * (hi,lo)
    __shared__ short Wlds[NFB * 512];       // 1 KB per fragment-block

    const int tid = threadIdx.x;
    const int wv  = tid >> 6;
    const int l   = tid & 63;
    const int lr  = l & 15;      // B-col (node) / A-row (feat) / D-col (node)
    const int lg  = l >> 4;      // k-group (8 consecutive k); D-row group
    const int n0  = blockIdx.x * 64 + wv * 16;
    const int node = n0 + lr;
    const bool nok = node < N_NODES;

    bf16x8 Xhi[NCH], Xlo[NCH];
    {
        const float* xr = xin + (size_t)(nok ? node : 0) * K + lg * 8;
        #pragma unroll
        for (int c = 0; c < NCH; c++) {
            float4 f0, f1;
            if (nok) {
                f0 = *(const float4*)(xr + c * 32);
                f1 = *(const float4*)(xr + c * 32 + 4);
            } else {
                f0 = make_float4(0.f, 0.f, 0.f, 0.f);
                f1 = f0;
            }
            float xv[8] = {f0.x, f0.y, f0.z, f0.w, f1.x, f1.y, f1.z, f1.w};
            #pragma unroll
            for (int j = 0; j < 8; j++) {
                unsigned short hb = f2bf(xv[j]);
                Xhi[c][j] = (short)hb;
                Xlo[c][j] = (short)f2bf(xv[j] - bf2f(hb));
            }
        }
    }

    const float* Bm[4] = {bq, bk, bv, bs};

    for (int mat = 0; mat < 4; mat++) {
        if (mat) __syncthreads();
        #pragma unroll
        for (int it = 0; it < NFB / 4; it++) {
            int fb   = it * 4 + wv;
            int hsel = fb & 1;
            int rest = fb >> 1;             // ft*NCH + c
            int c    = rest & (NCH - 1);
            int ft   = rest / NCH;
            const unsigned short* src = hsel ? wlo : whi;
            size_t goff = (size_t)(mat * 64 + ft * 16 + lr) * K + c * 32 + lg * 8;
            uint4 d = *(const uint4*)&src[goff];
            *(uint4*)&Wlds[fb * 512 + l * 8] = d;
        }
        __syncthreads();

        #pragma unroll
        for (int ft = 0; ft < 4; ft++) {
            f32x4 acc = {0.f, 0.f, 0.f, 0.f};
            #pragma unroll
            for (int c = 0; c < NCH; c++) {
                const int fb = (ft * NCH + c) << 1;
                bf16x8 Whi = *(const bf16x8*)&Wlds[fb * 512 + l * 8];
                bf16x8 Wlo = *(const bf16x8*)&Wlds[(fb + 1) * 512 + l * 8];
                acc = __builtin_amdgcn_mfma_f32_16x16x32_bf16(Whi, Xhi[c], acc, 0, 0, 0);
                acc = __builtin_amdgcn_mfma_f32_16x16x32_bf16(Wlo, Xhi[c], acc, 0, 0, 0);
                acc = __builtin_amdgcn_mfma_f32_16x16x32_bf16(Whi, Xlo[c], acc, 0, 0, 0);
            }
            if (nok) {
                float4 b4 = *(const float4*)&Bm[mat][ft * 16 + lg * 4];
                float v0 = acc[0] + b4.x;
                float v1 = acc[1] + b4.y;
                float v2 = acc[2] + b4.z;
                float v3 = acc[3] + b4.w;
                size_t off = (size_t)node * HDIM + ft * 16 + lg * 4;
                if (mat == 0) {
                    *(float4*)&q[off] = make_float4(v0, v1, v2, v3);
                } else if (mat == 3) {
                    *(float4*)&sk[off] = make_float4(v0, v1, v2, v3);
                } else {
                    unsigned p = pack4fp8(v0, v1, v2, v3);
                    if (mat == 1) *(unsigned*)&k8[off] = p;
                    else          *(unsigned*)&v8[off] = p;
                }
            }
        }
    }
}

// ---------- CSR build (padded buckets) ----------
__global__ void init_cursor(int* __restrict__ gcursor)
{
    int t = threadIdx.x;
    if (t < NBUCK) gcursor[t] = t * BCAP;
}

// packed entry: (dst_local << 17) | src
__global__ __launch_bounds__(256) void bucket_scatter(
    const int* __restrict__ ei, int* __restrict__ gcursor, int* __restrict__ bedge)
{
    __shared__ int hist[NBUCK];
    __shared__ int base[NBUCK];
    for (int i = threadIdx.x; i < NBUCK; i += 256) hist[i] = 0;
    __syncthreads();
    int e0 = blockIdx.x * EW_CHUNK;
    #pragma unroll
    for (int i = 0; i < EW_CHUNK / 256; i++) {
        int e = e0 + i * 256 + threadIdx.x;
        if (e < N_EDGES) atomicAdd(&hist[ei[N_EDGES + e] >> BSHIFT], 1);
    }
    __syncthreads();
    for (int i = threadIdx.x; i < NBUCK; i += 256)
        base[i] = hist[i] ? atomicAdd(&gcursor[i], hist[i]) : 0;
    __syncthreads();
    for (int i = threadIdx.x; i < NBUCK; i += 256) hist[i] = 0;
    __syncthreads();
    #pragma unroll
    for (int i = 0; i < EW_CHUNK / 256; i++) {
        int e = e0 + i * 256 + threadIdx.x;
        if (e < N_EDGES) {
            int src = ei[e];
            int dst = ei[N_EDGES + e];
            int b = dst >> BSHIFT;
            int pos = base[b] + atomicAdd(&hist[b], 1);
            bedge[pos] = ((dst & (BUCKET_NODES - 1)) << 17) | src;
        }
    }
}

// one WG per bucket: LDS hist -> scan -> row_beg/row_end (padded csr) -> place
__global__ __launch_bounds__(256) void csr_from_buckets(
    const int* __restrict__ bedge, const int* __restrict__ gcursor,
    int* __restrict__ row_beg, int* __restrict__ row_end,
    int* __restrict__ csr_src)
{
    __shared__ int cur[BUCKET_NODES];   // 512
    __shared__ int psum[256];
    const int b = blockIdx.x;
    const int dst0 = b << BSHIFT;
    const int t = threadIdx.x;
    const int beg = b * BCAP;
    const int cnt = gcursor[b] - beg;

    for (int i = t; i < BUCKET_NODES; i += 256) cur[i] = 0;
    __syncthreads();

    for (int i = t; i < cnt; i += 256)
        atomicAdd(&cur[bedge[beg + i] >> 17], 1);
    __syncthreads();

    int a0 = cur[2 * t], a1 = cur[2 * t + 1];
    int pair = a0 + a1;
    psum[t] = pair;
    __syncthreads();
    for (int off = 1; off < 256; off <<= 1) {
        int u = (t >= off) ? psum[t - off] : 0;
        __syncthreads();
        psum[t] += u;
        __syncthreads();
    }
    int ex = psum[t] - pair;            // exclusive prefix of this pair

    int d0 = dst0 + 2 * t, d1 = d0 + 1;
    int g0 = beg + ex, g1 = beg + ex + a0;
    if (d0 < N_NODES) { row_beg[d0] = g0; row_end[d0] = g0 + a0; }
    if (d1 < N_NODES) { row_beg[d1] = g1; row_end[d1] = g1 + a1; }
    cur[2 * t] = g0;
    cur[2 * t + 1] = g1;
    __syncthreads();

    for (int i = t; i < cnt; i += 256) {
        int ed = bedge[beg + i];
        int pos = atomicAdd(&cur[ed >> 17], 1);
        csr_src[pos] = ed & 0x1FFFF;
    }
}

// ---------- fused attention: wave per dst, 16 edges/iter, max-free, fp8 k/v ----------
// lane = g*8 + t : g = edge slot (0..7), t = feature octet (features 8t..8t+7)
__global__ __launch_bounds__(256) void attn_fused(
    const int* __restrict__ row_beg, const int* __restrict__ row_end,
    const int* __restrict__ csr_src,
    const float* __restrict__ q, const unsigned char* __restrict__ k8,
    const unsigned char* __restrict__ v8, const float* __restrict__ skip,
    float* __restrict__ hout, int do_relu)
{
    int n = blockIdx.x * 4 + (threadIdx.x >> 6);
    if (n >= N_NODES) return;
    int lane = threadIdx.x & 63;
    int g = lane >> 3;
    int t = lane & 7;
    int beg = row_beg[n], end = row_end[n];

    float qf[8];
    {
        const float* qrow = &q[(size_t)n * HDIM + t * 8];
        float4 f0 = *(const float4*)qrow;
        float4 f1 = *(const float4*)(qrow + 4);
        qf[0] = f0.x; qf[1] = f0.y; qf[2] = f0.z; qf[3] = f0.w;
        qf[4] = f1.x; qf[5] = f1.y; qf[6] = f1.z; qf[7] = f1.w;
    }

    float sA = 0.f, sB = 0.f;
    float acA[8] = {0.f, 0.f, 0.f, 0.f, 0.f, 0.f, 0.f, 0.f};
    float acB[8] = {0.f, 0.f, 0.f, 0.f, 0.f, 0.f, 0.f, 0.f};

    for (int i = beg; i < end; i += 16) {
        int eA = i + g;
        int eB = i + 8 + g;
        bool vA = (eA < end);
        bool vB = (eB < end);
        int srcA = csr_src[vA ? eA : beg];
        int srcB = csr_src[vB ? eB : beg];
        uint2 kuA = *(const uint2*)&k8[(size_t)srcA * HDIM + t * 8];
        uint2 vuA = *(const uint2*)&v8[(size_t)srcA * HDIM + t * 8];
        uint2 kuB = *(const uint2*)&k8[(size_t)srcB * HDIM + t * 8];
        uint2 vuB = *(const uint2*)&v8[(size_t)srcB * HDIM + t * 8];

        f32x2 kA0 = unpk_lo(kuA.x), kA1 = unpk_hi(kuA.x);
        f32x2 kA2 = unpk_lo(kuA.y), kA3 = unpk_hi(kuA.y);
        f32x2 kB0 = unpk_lo(kuB.x), kB1 = unpk_hi(kuB.x);
        f32x2 kB2 = unpk_lo(kuB.y), kB3 = unpk_hi(kuB.y);

        float pA = qf[0]*kA0[0] + qf[1]*kA0[1] + qf[2]*kA1[0] + qf[3]*kA1[1]
                 + qf[4]*kA2[0] + qf[5]*kA2[1] + qf[6]*kA3[0] + qf[7]*kA3[1];
        float pB = qf[0]*kB0[0] + qf[1]*kB0[1] + qf[2]*kB1[0] + qf[3]*kB1[1]
                 + qf[4]*kB2[0] + qf[5]*kB2[1] + qf[6]*kB3[0] + qf[7]*kB3[1];

        pA += __shfl_xor(pA, 1, 64);
        pB += __shfl_xor(pB, 1, 64);
        pA += __shfl_xor(pA, 2, 64);
        pB += __shfl_xor(pB, 2, 64);
        pA += __shfl_xor(pA, 4, 64);
        pB += __shfl_xor(pB, 4, 64);

        float ewA = __expf(vA ? pA * 0.125f : -INFINITY);   // 0 for invalid
        float ewB = __expf(vB ? pB * 0.125f : -INFINITY);
        sA += ewA;
        sB += ewB;

        f32x2 a0 = unpk_lo(vuA.x), a1 = unpk_hi(vuA.x);
        f32x2 a2 = unpk_lo(vuA.y), a3 = unpk_hi(vuA.y);
        f32x2 b0 = unpk_lo(vuB.x), b1 = unpk_hi(vuB.x);
        f32x2 b2 = unpk_lo(vuB.y), b3 = unpk_hi(vuB.y);
        acA[0] += a0[0] * ewA;  acB[0] += b0[0] * ewB;
        acA[1] += a0[1] * ewA;  acB[1] += b0[1] * ewB;
        acA[2] += a1[0] * ewA;  acB[2] += b1[0] * ewB;
        acA[3] += a1[1] * ewA;  acB[3] += b1[1] * ewB;
        acA[4] += a2[0] * ewA;  acB[4] += b2[0] * ewB;
        acA[5] += a2[1] * ewA;  acB[5] += b2[1] * ewB;
        acA[6] += a3[0] * ewA;  acB[6] += b3[0] * ewB;
        acA[7] += a3[1] * ewA;  acB[7] += b3[1] * ewB;
    }

    // lane-local merge of state B into A (pure adds)
    sA += sB;
    #pragma unroll
    for (int j = 0; j < 8; j++) acA[j] += acB[j];

    // cross-lane merge (offsets 8,16,32) — pure adds
    #pragma unroll
    for (int off = 8; off <= 32; off <<= 1) {
        sA += __shfl_xor(sA, off, 64);
        #pragma unroll
        for (int j = 0; j < 8; j++) acA[j] += __shfl_xor(acA[j], off, 64);
    }

    if (g == 0) {
        float inv = (sA > 0.f) ? (1.f / sA) : 0.f;
        const float* skrow = &skip[(size_t)n * HDIM + t * 8];
        float4 s0 = *(const float4*)skrow;
        float4 s1 = *(const float4*)(skrow + 4);
        float4 o0, o1;
        o0.x = acA[0] * inv + s0.x;
        o0.y = acA[1] * inv + s0.y;
        o0.z = acA[2] * inv + s0.z;
        o0.w = acA[3] * inv + s0.w;
        o1.x = acA[4] * inv + s1.x;
        o1.y = acA[5] * inv + s1.y;
        o1.z = acA[6] * inv + s1.z;
        o1.w = acA[7] * inv + s1.w;
        if (do_relu) {
            o0.x = fmaxf(o0.x, 0.f); o0.y = fmaxf(o0.y, 0.f);
            o0.z = fmaxf(o0.z, 0.f); o0.w = fmaxf(o0.w, 0.f);
            o1.x = fmaxf(o1.x, 0.f); o1.y = fmaxf(o1.y, 0.f);
            o1.z = fmaxf(o1.z, 0.f); o1.w = fmaxf(o1.w, 0.f);
        }
        float* orow = &hout[(size_t)n * HDIM + t * 8];
        *(float4*)orow = o0;
        *(float4*)(orow + 4) = o1;
    }
}

// ---------- mean pool: run-length accumulate (batch sorted), 64 nodes/wave ----------
__global__ __launch_bounds__(256) void pool_kernel(
    const float* __restrict__ h, const int* __restrict__ batch,
    float* __restrict__ sums, float* __restrict__ cnt)
{
    int wid = blockIdx.x * 4 + (threadIdx.x >> 6);
    int n0 = wid * 64;
    if (n0 >= N_NODES) return;
    int lane = threadIdx.x & 63;
    int nend = min(n0 + 64, N_NODES);
    float acc = 0.f;
    int b_cur = batch[n0];
    int run = 0;
    for (int n = n0; n < nend; n++) {
        int b = batch[n];
        if (b != b_cur) {
            atomicAdd(&sums[b_cur * HDIM + lane], acc);
            if (lane == 0) atomicAdd(&cnt[b_cur], (float)run);
            acc = 0.f; run = 0; b_cur = b;
        }
        acc += h[(size_t)n * HDIM + lane];
        run++;
    }
    atomicAdd(&sums[b_cur * HDIM + lane], acc);
    if (lane == 0) atomicAdd(&cnt[b_cur], (float)run);
}

// ---------- head ----------
__global__ void head_kernel(
    const float* __restrict__ sums, const float* __restrict__ cnt,
    const float* __restrict__ Wl, const float* __restrict__ bl,
    float* __restrict__ out)
{
    int tid = threadIdx.x;
    if (tid >= NB * NC) return;
    int b = tid / NC, c = tid % NC;
    float cc = fmaxf(cnt[b], 1.0f);
    float acc = bl[c];
    #pragma unroll
    for (int f = 0; f < HDIM; f++)
        acc += (sums[b * HDIM + f] / cc) * Wl[c * HDIM + f];
    out[tid] = acc;
}

extern "C" void kernel_launch(void* const* d_in, const int* in_sizes, int n_in,
                              void* d_out, int out_size, void* d_ws, size_t ws_size,
                              hipStream_t stream)
{
    const float* x     = (const float*)d_in[0];
    const int*   ei    = (const int*)d_in[1];
    const int*   batch = (const int*)d_in[2];

    const float* W[3][4];
    const float* B[3][4];
    for (int l = 0; l < 3; l++)
        for (int j = 0; j < 4; j++) {
            W[l][j] = (const float*)d_in[3 + l * 8 + j * 2];
            B[l][j] = (const float*)d_in[3 + l * 8 + j * 2 + 1];
        }
    const float* Wl = (const float*)d_in[27];
    const float* bl = (const float*)d_in[28];
    float* out = (float*)d_out;

    const size_t NF = (size_t)N_NODES * HDIM;
    char* w = (char*)d_ws;
    float*          h       = (float*)w;          w += NF * 4;
    float*          q       = (float*)w;          w += NF * 4;
    unsigned char*  k8      = (unsigned char*)w;  w += NF;
    unsigned char*  v8      = (unsigned char*)w;  w += NF;
    float*          skip    = (float*)w;          w += NF * 4;
    int*            csr_src = (int*)w;            w += (size_t)NBUCK * BCAP * 4;
    int*            bedge   = (int*)w;            w += (size_t)NBUCK * BCAP * 4;
    int*            row_bg  = (int*)w;            w += (size_t)N_NODES * 4;
    int*            row_en  = (int*)w;            w += (size_t)N_NODES * 4;
    int*            gcursor = (int*)w;            w += (size_t)NBUCK * 4;
    float*          sums    = (float*)w;          w += (size_t)NB * HDIM * 4;
    float*          cnt     = (float*)w;          w += (size_t)NB * 4;
    unsigned short* whi[3];
    unsigned short* wlo[3];
    const int wsz[3] = {64 * F_IN, 64 * HDIM, 64 * HDIM};   // per-mat elems
    for (int l = 0; l < 3; l++) {
        whi[l] = (unsigned short*)w; w += (size_t)4 * wsz[l] * 2;
        wlo[l] = (unsigned short*)w; w += (size_t)4 * wsz[l] * 2;
    }

    const int gemm_gx = (N_NODES + 63) / 64;
    const int node_gx = (N_NODES + 3) / 4;
    const int pool_gx = (N_NODES + 64 * 4 - 1) / (64 * 4);

    // ----- W split to bf16 hi/lo (once) -----
    for (int l = 0; l < 3; l++) {
        int n = wsz[l];
        wsplit<<<(4 * n + 255) / 256, 256, 0, stream>>>(
            W[l][0], W[l][1], W[l][2], W[l][3], whi[l], wlo[l], n);
    }

    // ----- CSR build via padded-bucket counting sort (once) -----
    init_cursor<<<1, 256, 0, stream>>>(gcursor);
    bucket_scatter<<<EW_GRID, 256, 0, stream>>>(ei, gcursor, bedge);
    csr_from_buckets<<<NBUCK, 256, 0, stream>>>(bedge, gcursor, row_bg, row_en, csr_src);

    for (int l = 0; l < 3; l++) {
        if (l == 0) {
            qkvs_gemm_mfma<F_IN><<<gemm_gx, 256, 0, stream>>>(
                x, whi[0], wlo[0], B[0][0], B[0][1], B[0][2], B[0][3],
                q, k8, v8, skip);
        } else {
            qkvs_gemm_mfma<HDIM><<<gemm_gx, 256, 0, stream>>>(
                h, whi[l], wlo[l], B[l][0], B[l][1], B[l][2], B[l][3],
                q, k8, v8, skip);
        }
        attn_fused<<<node_gx, 256, 0, stream>>>(
            row_bg, row_en, csr_src, q, k8, v8, skip, h, l < 2 ? 1 : 0);
    }

    hipMemsetAsync(sums, 0, (size_t)NB * HDIM * 4, stream);
    hipMemsetAsync(cnt,  0, (size_t)NB * 4, stream);
    pool_kernel<<<pool_gx, 256, 0, stream>>>(h, batch, sums, cnt);
    head_kernel<<<1, 640, 0, stream>>>(sums, cnt, Wl, bl, out);
}

// Round 24
// 386.688 us; speedup vs baseline: 1.3801x; 1.0045x over previous
//
#include <hip/hip_runtime.h>
#include <math.h>

#define N_NODES 100000
#define N_EDGES 1600000
#define NB 64
#define F_IN 128
#define HDIM 64
#define NC 10

#define BSHIFT 9
#define BUCKET_NODES (1 << BSHIFT)                          // 512
#define NBUCK ((N_NODES + BUCKET_NODES - 1) >> BSHIFT)      // 196
#define BCAP 16384                                          // padded bucket capacity
#define EW_CHUNK 4096
#define EW_GRID ((N_EDGES + EW_CHUNK - 1) / EW_CHUNK)       // 391
#define POOL_NPW 32

typedef __attribute__((ext_vector_type(8))) short bf16x8;
typedef __attribute__((ext_vector_type(4))) float f32x4;
typedef __attribute__((ext_vector_type(2))) float f32x2;
typedef _Float16 f16x2 __attribute__((ext_vector_type(2)));

// ---------- bf16 helpers (GEMM compute path) ----------
__device__ __forceinline__ unsigned short f2bf(float f) {
    unsigned u = __float_as_uint(f);
    u += 0x7FFFu + ((u >> 16) & 1u);    // round to nearest even
    return (unsigned short)(u >> 16);
}
__device__ __forceinline__ float bf2f(unsigned short b) {
    return __uint_as_float((unsigned)b << 16);
}

// ---------- fp16 helpers (q storage) ----------
__device__ __forceinline__ unsigned pack2h(float a, float b) {
    union { f16x2 h; unsigned u; } c;
    c.h[0] = (_Float16)a;
    c.h[1] = (_Float16)b;
    return c.u;
}
__device__ __forceinline__ f16x2 as_h2(unsigned u) {
    union { unsigned u; f16x2 h; } c;
    c.u = u;
    return c.h;
}

// ---------- fp8 helpers (k/v storage). `hi` operand must be immediate. ----------
#if __has_builtin(__builtin_amdgcn_cvt_pk_fp8_f32) && __has_builtin(__builtin_amdgcn_cvt_pk_f32_fp8)
__device__ __forceinline__ unsigned pack4fp8(float a, float b, float c, float d) {
    int r = 0;
    r = __builtin_amdgcn_cvt_pk_fp8_f32(a, b, r, false);   // low half
    r = __builtin_amdgcn_cvt_pk_fp8_f32(c, d, r, true);    // high half
    return (unsigned)r;
}
__device__ __forceinline__ f32x2 unpk_lo(unsigned u) {
    return __builtin_amdgcn_cvt_pk_f32_fp8((int)u, false);
}
__device__ __forceinline__ f32x2 unpk_hi(unsigned u) {
    return __builtin_amdgcn_cvt_pk_f32_fp8((int)u, true);
}
#else
__device__ __forceinline__ unsigned char f2e4m3(float f) {
    float a = fabsf(f);
    unsigned s = (__float_as_uint(f) >> 31) << 7;
    if (a > 448.f) a = 448.f;
    if (a < 0.015625f) {
        int qd = (int)(a * 512.f + 0.5f);
        if (qd > 7) qd = 7;
        return (unsigned char)(s | qd);
    }
    int e; float mf = frexpf(a, &e);
    int ee = e - 1 + 7;
    int m = (int)((mf * 2.f - 1.f) * 8.f + 0.5f);
    if (m > 7) { m = 0; ee++; }
    if (ee > 15) { ee = 15; m = 6; }
    return (unsigned char)(s | (ee << 3) | m);
}
__device__ __forceinline__ float e4m3_2f(unsigned char b) {
    unsigned s = b >> 7, e = (b >> 3) & 15, m = b & 7;
    float v = e ? ldexpf(1.f + m * 0.125f, (int)e - 7) : ldexpf((float)m, -9);
    return s ? -v : v;
}
__device__ __forceinline__ unsigned pack4fp8(float a, float b, float c, float d) {
    return (unsigned)f2e4m3(a) | ((unsigned)f2e4m3(b) << 8)
         | ((unsigned)f2e4m3(c) << 16) | ((unsigned)f2e4m3(d) << 24);
}
__device__ __forceinline__ f32x2 unpk_lo(unsigned u) {
    f32x2 r;
    r[0] = e4m3_2f((unsigned char)(u & 0xFF));
    r[1] = e4m3_2f((unsigned char)((u >> 8) & 0xFF));
    return r;
}
__device__ __forceinline__ f32x2 unpk_hi(unsigned u) {
    f32x2 r;
    r[0] = e4m3_2f((unsigned char)((u >> 16) & 0xFF));
    r[1] = e4m3_2f((unsigned char)((u >> 24) & 0xFF));
    return r;
}
#endif

// ---------- W split: W -> bf16 hi + bf16 lo (residual) ----------
__global__ __launch_bounds__(256) void wsplit(
    const float* __restrict__ W0, const float* __restrict__ W1,
    const float* __restrict__ W2, const float* __restrict__ W3,
    unsigned short* __restrict__ hi, unsigned short* __restrict__ lo, int n)
{
    int i = blockIdx.x * 256 + threadIdx.x;
    if (i >= 4 * n) return;
    const float* Ws[4] = {W0, W1, W2, W3};
    float w = Ws[i / n][i % n];
    unsigned short h = f2bf(w);
    hi[i] = h;
    lo[i] = f2bf(w - bf2f(h));
}

// ---------- fused q/k/v/skip GEMM via MFMA, OPERAND-SWAPPED ----------
// q emitted fp16 (64B gather-adjacent reads in attn); k/v fp8 e4m3; skip fp32.
template<int K>
__global__ __launch_bounds__(256) void qkvs_gemm_mfma(
    const float* __restrict__ xin,
    const unsigned short* __restrict__ whi,
    const unsigned short* __restrict__ wlo,
    const float* __restrict__ bq, const float* __restrict__ bk,
    const float* __restrict__ bv, const float* __restrict__ bs,
    unsigned short* __restrict__ q16, unsigned char* __restrict__ k8,
    unsigned char* __restrict__ v8, float* __restrict__ sk)
{
    constexpr int NCH = K / 32;
    constexpr int NFB = 4 * NCH * 2;        // per-mat: feat-tiles * chunks * (hi,lo)
    __shared__ short Wlds[NFB * 512];       // 1 KB per fragment-block

    const int tid = threadIdx.x;
    const int wv  = tid >> 6;
    const int l   = tid & 63;
    const int lr  = l & 15;      // B-col (node) / A-row (feat) / D-col (node)
    const int lg  = l >> 4;      // k-group (8 consecutive k); D-row group
    const int n0  = blockIdx.x * 64 + wv * 16;
    const int node = n0 + lr;
    const bool nok = node < N_NODES;

    bf16x8 Xhi[NCH], Xlo[NCH];
    {
        const float* xr = xin + (size_t)(nok ? node : 0) * K + lg * 8;
        #pragma unroll
        for (int c = 0; c < NCH; c++) {
            float4 f0, f1;
            if (nok) {
                f0 = *(const float4*)(xr + c * 32);
                f1 = *(const float4*)(xr + c * 32 + 4);
            } else {
                f0 = make_float4(0.f, 0.f, 0.f, 0.f);
                f1 = f0;
            }
            float xv[8] = {f0.x, f0.y, f0.z, f0.w, f1.x, f1.y, f1.z, f1.w};
            #pragma unroll
            for (int j = 0; j < 8; j++) {
                unsigned short hb = f2bf(xv[j]);
                Xhi[c][j] = (short)hb;
                Xlo[c][j] = (short)f2bf(xv[j] - bf2f(hb));
            }
        }
    }

    const float* Bm[4] = {bq, bk, bv, bs};

    for (int mat = 0; mat < 4; mat++) {
        if (mat) __syncthreads();
        #pragma unroll
        for (int it = 0; it < NFB / 4; it++) {
            int fb   = it * 4 + wv;
            int hsel = fb & 1;
            int rest = fb >> 1;             // ft*NCH + c
            int c    = rest & (NCH - 1);
            int ft   = rest / NCH;
            const unsigned short* src = hsel ? wlo : whi;
            size_t goff = (size_t)(mat * 64 + ft * 16 + lr) * K + c * 32 + lg * 8;
            uint4 d = *(const uint4*)&src[goff];
            *(uint4*)&Wlds[fb * 512 + l * 8] = d;
        }
        __syncthreads();

        #pragma unroll
        for (int ft = 0; ft < 4; ft++) {
            f32x4 acc = {0.f, 0.f, 0.f, 0.f};
            #pragma unroll
            for (int c = 0; c < NCH; c++) {
                const int fb = (ft * NCH + c) << 1;
                bf16x8 Whi = *(const bf16x8*)&Wlds[fb * 512 + l * 8];
                bf16x8 Wlo = *(const bf16x8*)&Wlds[(fb + 1) * 512 + l * 8];
                acc = __builtin_amdgcn_mfma_f32_16x16x32_bf16(Whi, Xhi[c], acc, 0, 0, 0);
                acc = __builtin_amdgcn_mfma_f32_16x16x32_bf16(Wlo, Xhi[c], acc, 0, 0, 0);
                acc = __builtin_amdgcn_mfma_f32_16x16x32_bf16(Whi, Xlo[c], acc, 0, 0, 0);
            }
            if (nok) {
                float4 b4 = *(const float4*)&Bm[mat][ft * 16 + lg * 4];
                float v0 = acc[0] + b4.x;
                float v1 = acc[1] + b4.y;
                float v2 = acc[2] + b4.z;
                float v3 = acc[3] + b4.w;
                size_t off = (size_t)node * HDIM + ft * 16 + lg * 4;
                if (mat == 0) {
                    uint2 p;
                    p.x = pack2h(v0, v1);
                    p.y = pack2h(v2, v3);
                    *(uint2*)&q16[off] = p;
                } else if (mat == 3) {
                    *(float4*)&sk[off] = make_float4(v0, v1, v2, v3);
                } else {
                    unsigned p = pack4fp8(v0, v1, v2, v3);
                    if (mat == 1) *(unsigned*)&k8[off] = p;
                    else          *(unsigned*)&v8[off] = p;
                }
            }
        }
    }
}

// ---------- CSR build (padded buckets) ----------
__global__ void init_cursor(int* __restrict__ gcursor)
{
    int t = threadIdx.x;
    if (t < NBUCK) gcursor[t] = t * BCAP;
}

// packed entry: (dst_local << 17) | src
__global__ __launch_bounds__(256) void bucket_scatter(
    const int* __restrict__ ei, int* __restrict__ gcursor, int* __restrict__ bedge)
{
    __shared__ int hist[NBUCK];
    __shared__ int base[NBUCK];
    for (int i = threadIdx.x; i < NBUCK; i += 256) hist[i] = 0;
    __syncthreads();
    int e0 = blockIdx.x * EW_CHUNK;
    #pragma unroll
    for (int i = 0; i < EW_CHUNK / 256; i++) {
        int e = e0 + i * 256 + threadIdx.x;
        if (e < N_EDGES) atomicAdd(&hist[ei[N_EDGES + e] >> BSHIFT], 1);
    }
    __syncthreads();
    for (int i = threadIdx.x; i < NBUCK; i += 256)
        base[i] = hist[i] ? atomicAdd(&gcursor[i], hist[i]) : 0;
    __syncthreads();
    for (int i = threadIdx.x; i < NBUCK; i += 256) hist[i] = 0;
    __syncthreads();
    #pragma unroll
    for (int i = 0; i < EW_CHUNK / 256; i++) {
        int e = e0 + i * 256 + threadIdx.x;
        if (e < N_EDGES) {
            int src = ei[e];
            int dst = ei[N_EDGES + e];
            int b = dst >> BSHIFT;
            int pos = base[b] + atomicAdd(&hist[b], 1);
            bedge[pos] = ((dst & (BUCKET_NODES - 1)) << 17) | src;
        }
    }
}

// one WG per bucket: LDS hist -> scan -> row_beg/row_end (padded csr) -> place
__global__ __launch_bounds__(256) void csr_from_buckets(
    const int* __restrict__ bedge, const int* __restrict__ gcursor,
    int* __restrict__ row_beg, int* __restrict__ row_end,
    int* __restrict__ csr_src)
{
    __shared__ int cur[BUCKET_NODES];   // 512
    __shared__ int psum[256];
    const int b = blockIdx.x;
    const int dst0 = b << BSHIFT;
    const int t = threadIdx.x;
    const int beg = b * BCAP;
    const int cnt = gcursor[b] - beg;

    for (int i = t; i < BUCKET_NODES; i += 256) cur[i] = 0;
    __syncthreads();

    for (int i = t; i < cnt; i += 256)
        atomicAdd(&cur[bedge[beg + i] >> 17], 1);
    __syncthreads();

    int a0 = cur[2 * t], a1 = cur[2 * t + 1];
    int pair = a0 + a1;
    psum[t] = pair;
    __syncthreads();
    for (int off = 1; off < 256; off <<= 1) {
        int u = (t >= off) ? psum[t - off] : 0;
        __syncthreads();
        psum[t] += u;
        __syncthreads();
    }
    int ex = psum[t] - pair;            // exclusive prefix of this pair

    int d0 = dst0 + 2 * t, d1 = d0 + 1;
    int g0 = beg + ex, g1 = beg + ex + a0;
    if (d0 < N_NODES) { row_beg[d0] = g0; row_end[d0] = g0 + a0; }
    if (d1 < N_NODES) { row_beg[d1] = g1; row_end[d1] = g1 + a1; }
    cur[2 * t] = g0;
    cur[2 * t + 1] = g1;
    __syncthreads();

    for (int i = t; i < cnt; i += 256) {
        int ed = bedge[beg + i];
        int pos = atomicAdd(&cur[ed >> 17], 1);
        csr_src[pos] = ed & 0x1FFFF;
    }
}

// ---------- fused attention: wave per dst, 16 edges/iter, max-free ----------
// q fp16, k/v fp8. lane = g*8 + t.
__global__ __launch_bounds__(256) void attn_fused(
    const int* __restrict__ row_beg, const int* __restrict__ row_end,
    const int* __restrict__ csr_src,
    const unsigned short* __restrict__ q16, const unsigned char* __restrict__ k8,
    const unsigned char* __restrict__ v8, const float* __restrict__ skip,
    float* __restrict__ hout, int do_relu)
{
    int n = blockIdx.x * 4 + (threadIdx.x >> 6);
    if (n >= N_NODES) return;
    int lane = threadIdx.x & 63;
    int g = lane >> 3;
    int t = lane & 7;
    int beg = row_beg[n], end = row_end[n];

    float qf[8];
    {
        uint4 qu = *(const uint4*)&q16[(size_t)n * HDIM + t * 8];
        f16x2 q0 = as_h2(qu.x), q1 = as_h2(qu.y), q2 = as_h2(qu.z), q3 = as_h2(qu.w);
        qf[0] = (float)q0[0]; qf[1] = (float)q0[1];
        qf[2] = (float)q1[0]; qf[3] = (float)q1[1];
        qf[4] = (float)q2[0]; qf[5] = (float)q2[1];
        qf[6] = (float)q3[0]; qf[7] = (float)q3[1];
    }

    float sA = 0.f, sB = 0.f;
    float acA[8] = {0.f, 0.f, 0.f, 0.f, 0.f, 0.f, 0.f, 0.f};
    float acB[8] = {0.f, 0.f, 0.f, 0.f, 0.f, 0.f, 0.f, 0.f};

    for (int i = beg; i < end; i += 16) {
        int eA = i + g;
        int eB = i + 8 + g;
        bool vA = (eA < end);
        bool vB = (eB < end);
        int srcA = csr_src[vA ? eA : beg];
        int srcB = csr_src[vB ? eB : beg];
        uint2 kuA = *(const uint2*)&k8[(size_t)srcA * HDIM + t * 8];
        uint2 vuA = *(const uint2*)&v8[(size_t)srcA * HDIM + t * 8];
        uint2 kuB = *(const uint2*)&k8[(size_t)srcB * HDIM + t * 8];
        uint2 vuB = *(const uint2*)&v8[(size_t)srcB * HDIM + t * 8];

        f32x2 kA0 = unpk_lo(kuA.x), kA1 = unpk_hi(kuA.x);
        f32x2 kA2 = unpk_lo(kuA.y), kA3 = unpk_hi(kuA.y);
        f32x2 kB0 = unpk_lo(kuB.x), kB1 = unpk_hi(kuB.x);
        f32x2 kB2 = unpk_lo(kuB.y), kB3 = unpk_hi(kuB.y);

        float pA = qf[0]*kA0[0] + qf[1]*kA0[1] + qf[2]*kA1[0] + qf[3]*kA1[1]
                 + qf[4]*kA2[0] + qf[5]*kA2[1] + qf[6]*kA3[0] + qf[7]*kA3[1];
        float pB = qf[0]*kB0[0] + qf[1]*kB0[1] + qf[2]*kB1[0] + qf[3]*kB1[1]
                 + qf[4]*kB2[0] + qf[5]*kB2[1] + qf[6]*kB3[0] + qf[7]*kB3[1];

        pA += __shfl_xor(pA, 1, 64);
        pB += __shfl_xor(pB, 1, 64);
        pA += __shfl_xor(pA, 2, 64);
        pB += __shfl_xor(pB, 2, 64);
        pA += __shfl_xor(pA, 4, 64);
        pB += __shfl_xor(pB, 4, 64);

        float ewA = __expf(vA ? pA * 0.125f : -INFINITY);   // 0 for invalid
        float ewB = __expf(vB ? pB * 0.125f : -INFINITY);
        sA += ewA;
        sB += ewB;

        f32x2 a0 = unpk_lo(vuA.x), a1 = unpk_hi(vuA.x);
        f32x2 a2 = unpk_lo(vuA.y), a3 = unpk_hi(vuA.y);
        f32x2 b0 = unpk_lo(vuB.x), b1 = unpk_hi(vuB.x);
        f32x2 b2 = unpk_lo(vuB.y), b3 = unpk_hi(vuB.y);
        acA[0] += a0[0] * ewA;  acB[0] += b0[0] * ewB;
        acA[1] += a0[1] * ewA;  acB[1] += b0[1] * ewB;
        acA[2] += a1[0] * ewA;  acB[2] += b1[0] * ewB;
        acA[3] += a1[1] * ewA;  acB[3] += b1[1] * ewB;
        acA[4] += a2[0] * ewA;  acB[4] += b2[0] * ewB;
        acA[5] += a2[1] * ewA;  acB[5] += b2[1] * ewB;
        acA[6] += a3[0] * ewA;  acB[6] += b3[0] * ewB;
        acA[7] += a3[1] * ewA;  acB[7] += b3[1] * ewB;
    }

    // lane-local merge of state B into A (pure adds)
    sA += sB;
    #pragma unroll
    for (int j = 0; j < 8; j++) acA[j] += acB[j];

    // cross-lane merge (offsets 8,16,32) — pure adds
    #pragma unroll
    for (int off = 8; off <= 32; off <<= 1) {
        sA += __shfl_xor(sA, off, 64);
        #pragma unroll
        for (int j = 0; j < 8; j++) acA[j] += __shfl_xor(acA[j], off, 64);
    }

    if (g == 0) {
        float inv = (sA > 0.f) ? (1.f / sA) : 0.f;
        const float* skrow = &skip[(size_t)n * HDIM + t * 8];
        float4 s0 = *(const float4*)skrow;
        float4 s1 = *(const float4*)(skrow + 4);
        float4 o0, o1;
        o0.x = acA[0] * inv + s0.x;
        o0.y = acA[1] * inv + s0.y;
        o0.z = acA[2] * inv + s0.z;
        o0.w = acA[3] * inv + s0.w;
        o1.x = acA[4] * inv + s1.x;
        o1.y = acA[5] * inv + s1.y;
        o1.z = acA[6] * inv + s1.z;
        o1.w = acA[7] * inv + s1.w;
        if (do_relu) {
            o0.x = fmaxf(o0.x, 0.f); o0.y = fmaxf(o0.y, 0.f);
            o0.z = fmaxf(o0.z, 0.f); o0.w = fmaxf(o0.w, 0.f);
            o1.x = fmaxf(o1.x, 0.f); o1.y = fmaxf(o1.y, 0.f);
            o1.z = fmaxf(o1.z, 0.f); o1.w = fmaxf(o1.w, 0.f);
        }
        float* orow = &hout[(size_t)n * HDIM + t * 8];
        *(float4*)orow = o0;
        *(float4*)(orow + 4) = o1;
    }
}

// ---------- mean pool: run-length accumulate (batch sorted), 32 nodes/wave ----------
__global__ __launch_bounds__(256) void pool_kernel(
    const float* __restrict__ h, const int* __restrict__ batch,
    float* __restrict__ sums, float* __restrict__ cnt)
{
    int wid = blockIdx.x * 4 + (threadIdx.x >> 6);
    int n0 = wid * POOL_NPW;
    if (n0 >= N_NODES) return;
    int lane = threadIdx.x & 63;
    int nend = min(n0 + POOL_NPW, N_NODES);
    float acc = 0.f;
    int b_cur = batch[n0];
    int run = 0;
    for (int n = n0; n < nend; n++) {
        int b = batch[n];
        if (b != b_cur) {
            atomicAdd(&sums[b_cur * HDIM + lane], acc);
            if (lane == 0) atomicAdd(&cnt[b_cur], (float)run);
            acc = 0.f; run = 0; b_cur = b;
        }
        acc += h[(size_t)n * HDIM + lane];
        run++;
    }
    atomicAdd(&sums[b_cur * HDIM + lane], acc);
    if (lane == 0) atomicAdd(&cnt[b_cur], (float)run);
}

// ---------- head ----------
__global__ void head_kernel(
    const float* __restrict__ sums, const float* __restrict__ cnt,
    const float* __restrict__ Wl, const float* __restrict__ bl,
    float* __restrict__ out)
{
    int tid = threadIdx.x;
    if (tid >= NB * NC) return;
    int b = tid / NC, c = tid % NC;
    float cc = fmaxf(cnt[b], 1.0f);
    float acc = bl[c];
    #pragma unroll
    for (int f = 0; f < HDIM; f++)
        acc += (sums[b * HDIM + f] / cc) * Wl[c * HDIM + f];
    out[tid] = acc;
}

extern "C" void kernel_launch(void* const* d_in, const int* in_sizes, int n_in,
                              void* d_out, int out_size, void* d_ws, size_t ws_size,
                              hipStream_t stream)
{
    const float* x     = (const float*)d_in[0];
    const int*   ei    = (const int*)d_in[1];
    const int*   batch = (const int*)d_in[2];

    const float* W[3][4];
    const float* B[3][4];
    for (int l = 0; l < 3; l++)
        for (int j = 0; j < 4; j++) {
            W[l][j] = (const float*)d_in[3 + l * 8 + j * 2];
            B[l][j] = (const float*)d_in[3 + l * 8 + j * 2 + 1];
        }
    const float* Wl = (const float*)d_in[27];
    const float* bl = (const float*)d_in[28];
    float* out = (float*)d_out;

    const size_t NF = (size_t)N_NODES * HDIM;
    char* w = (char*)d_ws;
    float*          h       = (float*)w;          w += NF * 4;
    unsigned short* q16     = (unsigned short*)w; w += NF * 2;
    unsigned char*  k8      = (unsigned char*)w;  w += NF;
    unsigned char*  v8      = (unsigned char*)w;  w += NF;
    float*          skip    = (float*)w;          w += NF * 4;
    int*            csr_src = (int*)w;            w += (size_t)NBUCK * BCAP * 4;
    int*            bedge   = (int*)w;            w += (size_t)NBUCK * BCAP * 4;
    int*            row_bg  = (int*)w;            w += (size_t)N_NODES * 4;
    int*            row_en  = (int*)w;            w += (size_t)N_NODES * 4;
    int*            gcursor = (int*)w;            w += (size_t)NBUCK * 4;
    float*          sums    = (float*)w;          w += (size_t)NB * HDIM * 4;
    float*          cnt     = (float*)w;          w += (size_t)NB * 4;
    unsigned short* whi[3];
    unsigned short* wlo[3];
    const int wsz[3] = {64 * F_IN, 64 * HDIM, 64 * HDIM};   // per-mat elems
    for (int l = 0; l < 3; l++) {
        whi[l] = (unsigned short*)w; w += (size_t)4 * wsz[l] * 2;
        wlo[l] = (unsigned short*)w; w += (size_t)4 * wsz[l] * 2;
    }

    const int gemm_gx = (N_NODES + 63) / 64;
    const int node_gx = (N_NODES + 3) / 4;
    const int pool_gx = (N_NODES + POOL_NPW * 4 - 1) / (POOL_NPW * 4);

    // ----- W split to bf16 hi/lo (once) -----
    for (int l = 0; l < 3; l++) {
        int n = wsz[l];
        wsplit<<<(4 * n + 255) / 256, 256, 0, stream>>>(
            W[l][0], W[l][1], W[l][2], W[l][3], whi[l], wlo[l], n);
    }

    // ----- CSR build via padded-bucket counting sort (once) -----
    init_cursor<<<1, 256, 0, stream>>>(gcursor);
    bucket_scatter<<<EW_GRID, 256, 0, stream>>>(ei, gcursor, bedge);
    csr_from_buckets<<<NBUCK, 256, 0, stream>>>(bedge, gcursor, row_bg, row_en, csr_src);

    for (int l = 0; l < 3; l++) {
        if (l == 0) {
            qkvs_gemm_mfma<F_IN><<<gemm_gx, 256, 0, stream>>>(
                x, whi[0], wlo[0], B[0][0], B[0][1], B[0][2], B[0][3],
                q16, k8, v8, skip);
        } else {
            qkvs_gemm_mfma<HDIM><<<gemm_gx, 256, 0, stream>>>(
                h, whi[l], wlo[l], B[l][0], B[l][1], B[l][2], B[l][3],
                q16, k8, v8, skip);
        }
        attn_fused<<<node_gx, 256, 0, stream>>>(
            row_bg, row_en, csr_src, q16, k8, v8, skip, h, l < 2 ? 1 : 0);
    }

    hipMemsetAsync(sums, 0, (size_t)NB * HDIM * 4, stream);
    hipMemsetAsync(cnt,  0, (size_t)NB * 4, stream);
    pool_kernel<<<pool_gx, 256, 0, stream>>>(h, batch, sums, cnt);
    head_kernel<<<1, 640, 0, stream>>>(sums, cnt, Wl, bl, out);
}